// Round 1
// baseline (6511.143 us; speedup 1.0000x reference)
//
#include <hip/hip_runtime.h>
#include <math.h>

#define NATOM 16384
#define NEDGE 262144
#define HID 128
#define NG 50
#define NI 6

__device__ __forceinline__ float ssp_f(float v) {
    // shifted softplus: log(1+exp(v)) - log(2), numerically stable
    return fmaxf(v, 0.0f) + log1pf(expf(-fabsf(v))) - 0.69314718055994531f;
}

// ---------------- edge precompute: d -> C[e], eaT[g][e] ----------------
__global__ void edge_pre(const float* __restrict__ pos, const int* __restrict__ ei,
                         float* __restrict__ eaT, float* __restrict__ Cb) {
    int e = blockIdx.x * 256 + threadIdx.x;
    if (e >= NEDGE) return;
    int s = ei[e], dd = ei[NEDGE + e];
    float dx = pos[3*s]   - pos[3*dd];
    float dy = pos[3*s+1] - pos[3*dd+1];
    float dz = pos[3*s+2] - pos[3*dd+2];
    float d = sqrtf(dx*dx + dy*dy + dz*dz);
    Cb[e] = 0.5f * (cosf(d * 0.31415926535897931f) + 1.0f);
    const float delta = 10.0f / 49.0f;
    const float coeff = -0.5f / (delta * delta);
    #pragma unroll
    for (int g = 0; g < NG; ++g) {
        float t = d - (float)g * delta;
        eaT[(size_t)g * NEDGE + e] = expf(coeff * t * t);
    }
}

// ---------------- embedding gather ----------------
__global__ void embed_k(const int* __restrict__ z, const float* __restrict__ emb,
                        float* __restrict__ h) {
    int tid = blockIdx.x * 256 + threadIdx.x;
    int n = tid >> 7, f = tid & 127;
    h[tid] = emb[z[n] * HID + f];
}

// ---------------- zero fill (float4 granular) ----------------
__global__ void fill0(float* __restrict__ p, int n4) {
    int i = blockIdx.x * 256 + threadIdx.x;
    if (i < n4) ((float4*)p)[i] = make_float4(0.f, 0.f, 0.f, 0.f);
}

// ---------------- node GEMM: C[M,128] = op(A[M,128]@B[128,128] + bias)(+res) ----------------
// tile 64m x 128n, 256 threads, micro 4x8, K=128 (B streamed in 32-k chunks)
__launch_bounds__(256)
__global__ void gemm_node(const float* __restrict__ A, const float* __restrict__ B,
                          const float* __restrict__ bias, const float* __restrict__ res,
                          float* __restrict__ Cout, int do_ssp) {
    __shared__ float at[128 * 68];   // at[k][m], m<64, pad 68
    __shared__ float bt[32 * 128];   // k-chunk of B
    int t = threadIdx.x;
    int mb = blockIdx.x * 64;
    // stage A with transpose (coalesced global, scatter to LDS)
    for (int i = t; i < 64 * 32; i += 256) {
        int r = i >> 5, kq = i & 31;
        float4 v = *(const float4*)&A[(size_t)(mb + r) * HID + kq * 4];
        at[(kq*4+0)*68 + r] = v.x;
        at[(kq*4+1)*68 + r] = v.y;
        at[(kq*4+2)*68 + r] = v.z;
        at[(kq*4+3)*68 + r] = v.w;
    }
    int tm = t & 15, tf = t >> 4;
    int m0 = tm * 4, f0 = tf * 8;
    float bv[8];
    #pragma unroll
    for (int j = 0; j < 8; ++j) bv[j] = bias ? bias[f0 + j] : 0.0f;
    float acc[4][8];
    #pragma unroll
    for (int a = 0; a < 4; ++a)
        #pragma unroll
        for (int j = 0; j < 8; ++j) acc[a][j] = 0.0f;

    for (int c = 0; c < 4; ++c) {
        __syncthreads();
        for (int i = t; i < 32 * 32; i += 256) {
            int kk = i >> 5, c4 = i & 31;
            *(float4*)&bt[kk*128 + c4*4] = *(const float4*)&B[(size_t)(c*32 + kk)*128 + c4*4];
        }
        __syncthreads();
        #pragma unroll
        for (int kk = 0; kk < 32; ++kk) {
            int k = c * 32 + kk;
            float4 a4 = *(const float4*)&at[k*68 + m0];
            float aa[4] = {a4.x, a4.y, a4.z, a4.w};
            float4 b0 = *(const float4*)&bt[kk*128 + f0];
            float4 b1 = *(const float4*)&bt[kk*128 + f0 + 4];
            float bb[8] = {b0.x, b0.y, b0.z, b0.w, b1.x, b1.y, b1.z, b1.w};
            #pragma unroll
            for (int a = 0; a < 4; ++a)
                #pragma unroll
                for (int j = 0; j < 8; ++j)
                    acc[a][j] = fmaf(aa[a], bb[j], acc[a][j]);
        }
    }
    // epilogue
    #pragma unroll
    for (int a = 0; a < 4; ++a) {
        size_t row = (size_t)(mb + m0 + a);
        float o[8];
        #pragma unroll
        for (int j = 0; j < 8; ++j) {
            float v = acc[a][j] + bv[j];
            o[j] = do_ssp ? ssp_f(v) : v;
        }
        if (res) {
            float4 r0 = *(const float4*)&res[row*128 + f0];
            float4 r1 = *(const float4*)&res[row*128 + f0 + 4];
            o[0]+=r0.x; o[1]+=r0.y; o[2]+=r0.z; o[3]+=r0.w;
            o[4]+=r1.x; o[5]+=r1.y; o[6]+=r1.z; o[7]+=r1.w;
        }
        *(float4*)&Cout[row*128 + f0]     = make_float4(o[0],o[1],o[2],o[3]);
        *(float4*)&Cout[row*128 + f0 + 4] = make_float4(o[4],o[5],o[6],o[7]);
    }
}

// ---------------- fused edge filter: per 64-edge tile ----------------
// T1 = ssp(ea@Wf1+bf1); filt = (T1@Wf2+bf2)*C; agg[dst] += x[src]*filt
__launch_bounds__(256)
__global__ void edge_filter(const float* __restrict__ eaT, const float* __restrict__ Cb,
                            const int* __restrict__ ei, const float* __restrict__ x,
                            float* __restrict__ agg,
                            const float* __restrict__ Wf1, const float* __restrict__ bf1,
                            const float* __restrict__ Wf2, const float* __restrict__ bf2) {
    __shared__ float buf[128 * 68];  // ea_t (50x68) then t1t (128x68)
    __shared__ float wch[32 * 128];  // weight k-chunk
    int t = threadIdx.x;
    int eb = blockIdx.x * 64;
    int te = t & 15, tf = t >> 4;
    int e0 = te * 4, f0 = tf * 8;

    // stage ea_t[k][e]: already k-major in global
    for (int i = t; i < 50 * 16; i += 256) {
        int g = i >> 4, c4 = i & 15;
        *(float4*)&buf[g*68 + c4*4] = *(const float4*)&eaT[(size_t)g*NEDGE + eb + c4*4];
    }

    float bv1[8], bv2[8];
    #pragma unroll
    for (int j = 0; j < 8; ++j) { bv1[j] = bf1[f0+j]; bv2[j] = bf2[f0+j]; }

    // GEMM1: [64,50]@[50,128], Wf1 streamed in 2 chunks of 25
    float acc1[4][8];
    #pragma unroll
    for (int a = 0; a < 4; ++a)
        #pragma unroll
        for (int j = 0; j < 8; ++j) acc1[a][j] = 0.0f;
    for (int c = 0; c < 2; ++c) {
        __syncthreads();
        for (int i = t; i < 25 * 32; i += 256) {
            int kk = i >> 5, c4 = i & 31;
            *(float4*)&wch[kk*128 + c4*4] = *(const float4*)&Wf1[(size_t)(c*25 + kk)*128 + c4*4];
        }
        __syncthreads();
        #pragma unroll
        for (int kk = 0; kk < 25; ++kk) {
            int k = c * 25 + kk;
            float4 a4 = *(const float4*)&buf[k*68 + e0];
            float aa[4] = {a4.x, a4.y, a4.z, a4.w};
            float4 b0 = *(const float4*)&wch[kk*128 + f0];
            float4 b1 = *(const float4*)&wch[kk*128 + f0 + 4];
            float bb[8] = {b0.x, b0.y, b0.z, b0.w, b1.x, b1.y, b1.z, b1.w};
            #pragma unroll
            for (int a = 0; a < 4; ++a)
                #pragma unroll
                for (int j = 0; j < 8; ++j)
                    acc1[a][j] = fmaf(aa[a], bb[j], acc1[a][j]);
        }
    }
    __syncthreads();  // all GEMM1 reads of buf done
    // ssp + transpose into buf as t1t[f][e]
    #pragma unroll
    for (int j = 0; j < 8; ++j) {
        float4 w;
        w.x = ssp_f(acc1[0][j] + bv1[j]);
        w.y = ssp_f(acc1[1][j] + bv1[j]);
        w.z = ssp_f(acc1[2][j] + bv1[j]);
        w.w = ssp_f(acc1[3][j] + bv1[j]);
        *(float4*)&buf[(f0 + j)*68 + e0] = w;
    }

    // GEMM2: [64,128]@[128,128], Wf2 streamed in 4 chunks of 32
    float acc2[4][8];
    #pragma unroll
    for (int a = 0; a < 4; ++a)
        #pragma unroll
        for (int j = 0; j < 8; ++j) acc2[a][j] = 0.0f;
    for (int c = 0; c < 4; ++c) {
        __syncthreads();
        for (int i = t; i < 32 * 32; i += 256) {
            int kk = i >> 5, c4 = i & 31;
            *(float4*)&wch[kk*128 + c4*4] = *(const float4*)&Wf2[(size_t)(c*32 + kk)*128 + c4*4];
        }
        __syncthreads();
        #pragma unroll
        for (int kk = 0; kk < 32; ++kk) {
            float4 a4 = *(const float4*)&buf[(c*32 + kk)*68 + e0];
            float aa[4] = {a4.x, a4.y, a4.z, a4.w};
            float4 b0 = *(const float4*)&wch[kk*128 + f0];
            float4 b1 = *(const float4*)&wch[kk*128 + f0 + 4];
            float bb[8] = {b0.x, b0.y, b0.z, b0.w, b1.x, b1.y, b1.z, b1.w};
            #pragma unroll
            for (int a = 0; a < 4; ++a)
                #pragma unroll
                for (int j = 0; j < 8; ++j)
                    acc2[a][j] = fmaf(aa[a], bb[j], acc2[a][j]);
        }
    }
    // epilogue: scale by C, gather x[src], scatter-add to agg[dst]
    #pragma unroll
    for (int a = 0; a < 4; ++a) {
        int e = eb + e0 + a;
        int s = ei[e], dd = ei[NEDGE + e];
        float ce = Cb[e];
        const float* xr = &x[(size_t)s * HID + f0];
        float* ar = &agg[(size_t)dd * HID + f0];
        float4 x0 = *(const float4*)&xr[0];
        float4 x1 = *(const float4*)&xr[4];
        float xx[8] = {x0.x, x0.y, x0.z, x0.w, x1.x, x1.y, x1.z, x1.w};
        #pragma unroll
        for (int j = 0; j < 8; ++j) {
            float flt = (acc2[a][j] + bv2[j]) * ce;
            atomicAdd(&ar[j], flt * xx[j]);
        }
    }
}

// ---------------- readout ----------------
__launch_bounds__(256)
__global__ void readout1(const float* __restrict__ h, const float* __restrict__ Wo1,
                         const float* __restrict__ bo1, const float* __restrict__ Wo2,
                         const float* __restrict__ bo2, float* __restrict__ accum) {
    __shared__ float w1[128 * 64];
    int t = threadIdx.x;
    for (int i = t; i < 128 * 16; i += 256)
        ((float4*)w1)[i] = ((const float4*)Wo1)[i];
    __syncthreads();
    int f = t & 63, a = t >> 6;
    int n = blockIdx.x * 4 + a;
    float acc = bo1[f];
    #pragma unroll 8
    for (int k = 0; k < 128; ++k)
        acc = fmaf(h[(size_t)n * HID + k], w1[k*64 + f], acc);
    float u = ssp_f(acc) * Wo2[f];
    #pragma unroll
    for (int off = 32; off > 0; off >>= 1)
        u += __shfl_down(u, off, 64);
    if (f == 0) atomicAdd(accum, u + bo2[0]);
}

__global__ void readout2(const float* __restrict__ accum, float* __restrict__ out) {
    out[0] = fmaxf(accum[0], 0.0f);
}

extern "C" void kernel_launch(void* const* d_in, const int* in_sizes, int n_in,
                              void* d_out, int out_size, void* d_ws, size_t ws_size,
                              hipStream_t stream) {
    const int*   z   = (const int*)d_in[0];
    const float* pos = (const float*)d_in[1];
    const int*   ei  = (const int*)d_in[2];
    const float* emb = (const float*)d_in[3];
    const float* Wf1 = (const float*)d_in[4];
    const float* bf1 = (const float*)d_in[5];
    const float* Wf2 = (const float*)d_in[6];
    const float* bf2 = (const float*)d_in[7];
    const float* Wl1 = (const float*)d_in[8];
    const float* Wl2 = (const float*)d_in[9];
    const float* bl2 = (const float*)d_in[10];
    const float* Wl  = (const float*)d_in[11];
    const float* bl  = (const float*)d_in[12];
    const float* Wo1 = (const float*)d_in[13];
    const float* bo1 = (const float*)d_in[14];
    const float* Wo2 = (const float*)d_in[15];
    const float* bo2 = (const float*)d_in[16];
    float* out = (float*)d_out;

    float* ws  = (float*)d_ws;
    float* eaT = ws;                                    // 50*E
    float* Cb  = eaT + (size_t)NG * NEDGE;              // E
    float* h   = Cb  + NEDGE;                           // N*HID
    float* x   = h   + (size_t)NATOM * HID;
    float* agg = x   + (size_t)NATOM * HID;
    float* tb  = agg + (size_t)NATOM * HID;
    float* accum = tb + (size_t)NATOM * HID;            // 4 floats

    edge_pre<<<NEDGE/256, 256, 0, stream>>>(pos, ei, eaT, Cb);
    embed_k<<<(NATOM*HID)/256, 256, 0, stream>>>(z, emb, h);
    for (int i = 0; i < NI; ++i) {
        gemm_node<<<NATOM/64, 256, 0, stream>>>(h, Wl1 + (size_t)i*HID*HID, nullptr, nullptr, x, 0);
        fill0<<<(NATOM*HID/4)/256, 256, 0, stream>>>(agg, NATOM*HID/4);
        edge_filter<<<NEDGE/64, 256, 0, stream>>>(eaT, Cb, ei, x, agg,
            Wf1 + (size_t)i*NG*HID, bf1 + i*HID,
            Wf2 + (size_t)i*HID*HID, bf2 + i*HID);
        gemm_node<<<NATOM/64, 256, 0, stream>>>(agg, Wl2 + (size_t)i*HID*HID, bl2 + i*HID, nullptr, tb, 1);
        gemm_node<<<NATOM/64, 256, 0, stream>>>(tb, Wl + (size_t)i*HID*HID, bl + i*HID, h, h, 0);
    }
    fill0<<<1, 256, 0, stream>>>(accum, 1);
    readout1<<<NATOM/4, 256, 0, stream>>>(h, Wo1, bo1, Wo2, bo2, accum);
    readout2<<<1, 1, 0, stream>>>(accum, out);
}

// Round 2
// 2292.362 us; speedup vs baseline: 2.8404x; 2.8404x over previous
//
#include <hip/hip_runtime.h>
#include <math.h>

#define NATOM 16384
#define NEDGE 262144
#define HID 128
#define NG 50
#define NI 6

__device__ __forceinline__ float ssp_f(float v) {
    return fmaxf(v, 0.0f) + log1pf(expf(-fabsf(v))) - 0.69314718055994531f;
}

// ---------------- counting sort by dst ----------------
__global__ void fill0(float* __restrict__ p, int n4) {
    int i = blockIdx.x * 256 + threadIdx.x;
    if (i < n4) ((float4*)p)[i] = make_float4(0.f, 0.f, 0.f, 0.f);
}

__global__ void hist_k(const int* __restrict__ ei, int* __restrict__ cnt) {
    int e = blockIdx.x * 256 + threadIdx.x;
    if (e < NEDGE) atomicAdd(&cnt[ei[NEDGE + e]], 1);
}

__global__ void scan_k(const int* __restrict__ cnt, int* __restrict__ offs) {
    __shared__ int part[256];
    int t = threadIdx.x;
    int base = t * 64;
    int s = 0;
    for (int i = 0; i < 64; ++i) s += cnt[base + i];
    part[t] = s;
    __syncthreads();
    for (int off = 1; off < 256; off <<= 1) {
        int v = (t >= off) ? part[t - off] : 0;
        __syncthreads();
        part[t] += v;
        __syncthreads();
    }
    int r = part[t] - s;  // exclusive prefix of this chunk
    for (int i = 0; i < 64; ++i) { offs[base + i] = r; r += cnt[base + i]; }
    if (t == 255) offs[NATOM] = r;
}

__global__ void scatter_k(const int* __restrict__ ei, const int* __restrict__ offs,
                          int* __restrict__ cnt, int* __restrict__ perm) {
    int e = blockIdx.x * 256 + threadIdx.x;
    if (e >= NEDGE) return;
    int d = ei[NEDGE + e];
    int r = atomicAdd(&cnt[d], 1);
    perm[offs[d] + r] = e;
}

// ---------------- edge precompute in sorted order ----------------
__global__ void edge_pre(const float* __restrict__ pos, const int* __restrict__ ei,
                         const int* __restrict__ perm,
                         float* __restrict__ eaT, float* __restrict__ Cb,
                         int* __restrict__ sSrc, int* __restrict__ sDst) {
    int j = blockIdx.x * 256 + threadIdx.x;
    if (j >= NEDGE) return;
    int e = perm[j];
    int s = ei[e], dd = ei[NEDGE + e];
    sSrc[j] = s; sDst[j] = dd;
    float dx = pos[3*s]   - pos[3*dd];
    float dy = pos[3*s+1] - pos[3*dd+1];
    float dz = pos[3*s+2] - pos[3*dd+2];
    float d = sqrtf(dx*dx + dy*dy + dz*dz);
    Cb[j] = 0.5f * (cosf(d * 0.31415926535897931f) + 1.0f);
    const float delta = 10.0f / 49.0f;
    const float coeff = -0.5f / (delta * delta);
    #pragma unroll
    for (int g = 0; g < NG; ++g) {
        float t = d - (float)g * delta;
        eaT[(size_t)g * NEDGE + j] = expf(coeff * t * t);
    }
}

// ---------------- embedding gather ----------------
__global__ void embed_k(const int* __restrict__ z, const float* __restrict__ emb,
                        float* __restrict__ h) {
    int tid = blockIdx.x * 256 + threadIdx.x;
    int n = tid >> 7, f = tid & 127;
    h[tid] = emb[z[n] * HID + f];
}

// ---------------- node GEMM ----------------
__launch_bounds__(256)
__global__ void gemm_node(const float* __restrict__ A, const float* __restrict__ B,
                          const float* __restrict__ bias, const float* __restrict__ res,
                          float* __restrict__ Cout, int do_ssp) {
    __shared__ float at[128 * 68];
    __shared__ float bt[32 * 128];
    int t = threadIdx.x;
    int mb = blockIdx.x * 64;
    for (int i = t; i < 64 * 32; i += 256) {
        int r = i >> 5, kq = i & 31;
        float4 v = *(const float4*)&A[(size_t)(mb + r) * HID + kq * 4];
        at[(kq*4+0)*68 + r] = v.x;
        at[(kq*4+1)*68 + r] = v.y;
        at[(kq*4+2)*68 + r] = v.z;
        at[(kq*4+3)*68 + r] = v.w;
    }
    int tm = t & 15, tf = t >> 4;
    int m0 = tm * 4, f0 = tf * 8;
    float bv[8];
    #pragma unroll
    for (int j = 0; j < 8; ++j) bv[j] = bias ? bias[f0 + j] : 0.0f;
    float acc[4][8];
    #pragma unroll
    for (int a = 0; a < 4; ++a)
        #pragma unroll
        for (int j = 0; j < 8; ++j) acc[a][j] = 0.0f;

    for (int c = 0; c < 4; ++c) {
        __syncthreads();
        for (int i = t; i < 32 * 32; i += 256) {
            int kk = i >> 5, c4 = i & 31;
            *(float4*)&bt[kk*128 + c4*4] = *(const float4*)&B[(size_t)(c*32 + kk)*128 + c4*4];
        }
        __syncthreads();
        #pragma unroll
        for (int kk = 0; kk < 32; ++kk) {
            int k = c * 32 + kk;
            float4 a4 = *(const float4*)&at[k*68 + m0];
            float aa[4] = {a4.x, a4.y, a4.z, a4.w};
            float4 b0 = *(const float4*)&bt[kk*128 + f0];
            float4 b1 = *(const float4*)&bt[kk*128 + f0 + 4];
            float bb[8] = {b0.x, b0.y, b0.z, b0.w, b1.x, b1.y, b1.z, b1.w};
            #pragma unroll
            for (int a = 0; a < 4; ++a)
                #pragma unroll
                for (int j = 0; j < 8; ++j)
                    acc[a][j] = fmaf(aa[a], bb[j], acc[a][j]);
        }
    }
    #pragma unroll
    for (int a = 0; a < 4; ++a) {
        size_t row = (size_t)(mb + m0 + a);
        float o[8];
        #pragma unroll
        for (int j = 0; j < 8; ++j) {
            float v = acc[a][j] + bv[j];
            o[j] = do_ssp ? ssp_f(v) : v;
        }
        if (res) {
            float4 r0 = *(const float4*)&res[row*128 + f0];
            float4 r1 = *(const float4*)&res[row*128 + f0 + 4];
            o[0]+=r0.x; o[1]+=r0.y; o[2]+=r0.z; o[3]+=r0.w;
            o[4]+=r1.x; o[5]+=r1.y; o[6]+=r1.z; o[7]+=r1.w;
        }
        *(float4*)&Cout[row*128 + f0]     = make_float4(o[0],o[1],o[2],o[3]);
        *(float4*)&Cout[row*128 + f0 + 4] = make_float4(o[4],o[5],o[6],o[7]);
    }
}

// ---------------- fused edge filter, sorted edges, segmented reduction ----------------
#define MROW 132  // msg row stride (132 % 32 == 4 -> conflict-light)
__launch_bounds__(256)
__global__ void edge_filter(const float* __restrict__ eaT, const float* __restrict__ Cb,
                            const int* __restrict__ sSrc, const int* __restrict__ sDst,
                            const float* __restrict__ x, float* __restrict__ agg,
                            const float* __restrict__ Wf1, const float* __restrict__ bf1,
                            const float* __restrict__ Wf2, const float* __restrict__ bf2) {
    __shared__ float buf[128 * 68];  // ea_t (50x68) -> t1t (128x68) -> msg (64x132)
    __shared__ float wch[32 * 128];
    __shared__ int dstl[64];
    int t = threadIdx.x;
    int eb = blockIdx.x * 64;
    int te = t & 15, tf = t >> 4;
    int e0 = te * 4, f0 = tf * 8;

    for (int i = t; i < 50 * 16; i += 256) {
        int g = i >> 4, c4 = i & 15;
        *(float4*)&buf[g*68 + c4*4] = *(const float4*)&eaT[(size_t)g*NEDGE + eb + c4*4];
    }

    float bv1[8], bv2[8];
    #pragma unroll
    for (int j = 0; j < 8; ++j) { bv1[j] = bf1[f0+j]; bv2[j] = bf2[f0+j]; }

    // GEMM1: [64,50] @ [50,128]
    float acc1[4][8];
    #pragma unroll
    for (int a = 0; a < 4; ++a)
        #pragma unroll
        for (int j = 0; j < 8; ++j) acc1[a][j] = 0.0f;
    for (int c = 0; c < 2; ++c) {
        __syncthreads();
        for (int i = t; i < 25 * 32; i += 256) {
            int kk = i >> 5, c4 = i & 31;
            *(float4*)&wch[kk*128 + c4*4] = *(const float4*)&Wf1[(size_t)(c*25 + kk)*128 + c4*4];
        }
        __syncthreads();
        #pragma unroll
        for (int kk = 0; kk < 25; ++kk) {
            int k = c * 25 + kk;
            float4 a4 = *(const float4*)&buf[k*68 + e0];
            float aa[4] = {a4.x, a4.y, a4.z, a4.w};
            float4 b0 = *(const float4*)&wch[kk*128 + f0];
            float4 b1 = *(const float4*)&wch[kk*128 + f0 + 4];
            float bb[8] = {b0.x, b0.y, b0.z, b0.w, b1.x, b1.y, b1.z, b1.w};
            #pragma unroll
            for (int a = 0; a < 4; ++a)
                #pragma unroll
                for (int j = 0; j < 8; ++j)
                    acc1[a][j] = fmaf(aa[a], bb[j], acc1[a][j]);
        }
    }
    __syncthreads();
    #pragma unroll
    for (int j = 0; j < 8; ++j) {
        float4 w;
        w.x = ssp_f(acc1[0][j] + bv1[j]);
        w.y = ssp_f(acc1[1][j] + bv1[j]);
        w.z = ssp_f(acc1[2][j] + bv1[j]);
        w.w = ssp_f(acc1[3][j] + bv1[j]);
        *(float4*)&buf[(f0 + j)*68 + e0] = w;
    }

    // GEMM2: [64,128] @ [128,128]
    float acc2[4][8];
    #pragma unroll
    for (int a = 0; a < 4; ++a)
        #pragma unroll
        for (int j = 0; j < 8; ++j) acc2[a][j] = 0.0f;
    for (int c = 0; c < 4; ++c) {
        __syncthreads();
        for (int i = t; i < 32 * 32; i += 256) {
            int kk = i >> 5, c4 = i & 31;
            *(float4*)&wch[kk*128 + c4*4] = *(const float4*)&Wf2[(size_t)(c*32 + kk)*128 + c4*4];
        }
        __syncthreads();
        #pragma unroll
        for (int kk = 0; kk < 32; ++kk) {
            float4 a4 = *(const float4*)&buf[(c*32 + kk)*68 + e0];
            float aa[4] = {a4.x, a4.y, a4.z, a4.w};
            float4 b0 = *(const float4*)&wch[kk*128 + f0];
            float4 b1 = *(const float4*)&wch[kk*128 + f0 + 4];
            float bb[8] = {b0.x, b0.y, b0.z, b0.w, b1.x, b1.y, b1.z, b1.w};
            #pragma unroll
            for (int a = 0; a < 4; ++a)
                #pragma unroll
                for (int j = 0; j < 8; ++j)
                    acc2[a][j] = fmaf(aa[a], bb[j], acc2[a][j]);
        }
    }
    __syncthreads();  // done reading buf as t1t

    // write msg = (acc2+b)*C*x[src] into LDS
    if (t < 64) dstl[t] = sDst[eb + t];
    #pragma unroll
    for (int a = 0; a < 4; ++a) {
        int e = eb + e0 + a;
        int s = sSrc[e];
        float ce = Cb[e];
        const float* xr = &x[(size_t)s * HID + f0];
        float4 x0 = *(const float4*)&xr[0];
        float4 x1 = *(const float4*)&xr[4];
        float xx[8] = {x0.x, x0.y, x0.z, x0.w, x1.x, x1.y, x1.z, x1.w};
        float o[8];
        #pragma unroll
        for (int j = 0; j < 8; ++j)
            o[j] = (acc2[a][j] + bv2[j]) * ce * xx[j];
        *(float4*)&buf[(e0+a)*MROW + f0]     = make_float4(o[0],o[1],o[2],o[3]);
        *(float4*)&buf[(e0+a)*MROW + f0 + 4] = make_float4(o[4],o[5],o[6],o[7]);
    }
    __syncthreads();

    // segmented reduction: 128 cols x 2 halves; branch is wave-uniform
    int f = t & 127, half = t >> 7;
    int ib = half * 32;
    float run = 0.0f;
    int cur = dstl[ib];
    for (int i = ib; i < ib + 32; ++i) {
        int dnow = dstl[i];
        if (dnow != cur) {
            atomicAdd(&agg[(size_t)cur * HID + f], run);
            run = 0.0f;
            cur = dnow;
        }
        run += buf[i*MROW + f];
    }
    atomicAdd(&agg[(size_t)cur * HID + f], run);
}

// ---------------- readout ----------------
__launch_bounds__(256)
__global__ void readout1(const float* __restrict__ h, const float* __restrict__ Wo1,
                         const float* __restrict__ bo1, const float* __restrict__ Wo2,
                         const float* __restrict__ bo2, float* __restrict__ accum) {
    __shared__ float w1[128 * 64];
    int t = threadIdx.x;
    for (int i = t; i < 128 * 16; i += 256)
        ((float4*)w1)[i] = ((const float4*)Wo1)[i];
    __syncthreads();
    int f = t & 63, a = t >> 6;
    int n = blockIdx.x * 4 + a;
    float acc = bo1[f];
    #pragma unroll 8
    for (int k = 0; k < 128; ++k)
        acc = fmaf(h[(size_t)n * HID + k], w1[k*64 + f], acc);
    float u = ssp_f(acc) * Wo2[f];
    #pragma unroll
    for (int off = 32; off > 0; off >>= 1)
        u += __shfl_down(u, off, 64);
    if (f == 0) atomicAdd(accum, u + bo2[0]);
}

__global__ void readout2(const float* __restrict__ accum, float* __restrict__ out) {
    out[0] = fmaxf(accum[0], 0.0f);
}

extern "C" void kernel_launch(void* const* d_in, const int* in_sizes, int n_in,
                              void* d_out, int out_size, void* d_ws, size_t ws_size,
                              hipStream_t stream) {
    const int*   z   = (const int*)d_in[0];
    const float* pos = (const float*)d_in[1];
    const int*   ei  = (const int*)d_in[2];
    const float* emb = (const float*)d_in[3];
    const float* Wf1 = (const float*)d_in[4];
    const float* bf1 = (const float*)d_in[5];
    const float* Wf2 = (const float*)d_in[6];
    const float* bf2 = (const float*)d_in[7];
    const float* Wl1 = (const float*)d_in[8];
    const float* Wl2 = (const float*)d_in[9];
    const float* bl2 = (const float*)d_in[10];
    const float* Wl  = (const float*)d_in[11];
    const float* bl  = (const float*)d_in[12];
    const float* Wo1 = (const float*)d_in[13];
    const float* bo1 = (const float*)d_in[14];
    const float* Wo2 = (const float*)d_in[15];
    const float* bo2 = (const float*)d_in[16];
    float* out = (float*)d_out;

    float* ws  = (float*)d_ws;
    float* eaT = ws;                                    // 50*E
    float* Cb  = eaT + (size_t)NG * NEDGE;              // E
    float* h   = Cb  + NEDGE;                           // N*HID
    float* x   = h   + (size_t)NATOM * HID;
    float* agg = x   + (size_t)NATOM * HID;
    float* tb  = agg + (size_t)NATOM * HID;
    float* accum = tb + (size_t)NATOM * HID;            // 4 floats
    int* cnt  = (int*)(accum + 4);                      // N
    int* offs = cnt + NATOM;                            // N+4
    int* perm = offs + NATOM + 4;                       // E
    int* sSrc = perm + NEDGE;                           // E
    int* sDst = sSrc + NEDGE;                           // E

    // counting sort by dst
    fill0<<<NATOM/4/256, 256, 0, stream>>>((float*)cnt, NATOM/4);
    hist_k<<<NEDGE/256, 256, 0, stream>>>(ei, cnt);
    scan_k<<<1, 256, 0, stream>>>(cnt, offs);
    fill0<<<NATOM/4/256, 256, 0, stream>>>((float*)cnt, NATOM/4);
    scatter_k<<<NEDGE/256, 256, 0, stream>>>(ei, offs, cnt, perm);

    edge_pre<<<NEDGE/256, 256, 0, stream>>>(pos, ei, perm, eaT, Cb, sSrc, sDst);
    embed_k<<<(NATOM*HID)/256, 256, 0, stream>>>(z, emb, h);
    for (int i = 0; i < NI; ++i) {
        gemm_node<<<NATOM/64, 256, 0, stream>>>(h, Wl1 + (size_t)i*HID*HID, nullptr, nullptr, x, 0);
        fill0<<<(NATOM*HID/4)/256, 256, 0, stream>>>(agg, NATOM*HID/4);
        edge_filter<<<NEDGE/64, 256, 0, stream>>>(eaT, Cb, sSrc, sDst, x, agg,
            Wf1 + (size_t)i*NG*HID, bf1 + i*HID,
            Wf2 + (size_t)i*HID*HID, bf2 + i*HID);
        gemm_node<<<NATOM/64, 256, 0, stream>>>(agg, Wl2 + (size_t)i*HID*HID, bl2 + i*HID, nullptr, tb, 1);
        gemm_node<<<NATOM/64, 256, 0, stream>>>(tb, Wl + (size_t)i*HID*HID, bl + i*HID, h, h, 0);
    }
    fill0<<<1, 256, 0, stream>>>(accum, 1);
    readout1<<<NATOM/4, 256, 0, stream>>>(h, Wo1, bo1, Wo2, bo2, accum);
    readout2<<<1, 1, 0, stream>>>(accum, out);
}

// Round 3
// 1706.440 us; speedup vs baseline: 3.8156x; 1.3434x over previous
//
#include <hip/hip_runtime.h>
#include <math.h>

#define NATOM 16384
#define NEDGE 262144
#define HID 128
#define NG 50
#define NI 6

typedef _Float16 h8_t __attribute__((ext_vector_type(8)));
typedef _Float16 h4_t __attribute__((ext_vector_type(4)));
typedef float    f4_t __attribute__((ext_vector_type(4)));

__device__ __forceinline__ float ssp_f(float v) {
    return fmaxf(v, 0.0f) + log1pf(expf(-fabsf(v))) - 0.69314718055994531f;
}

// ---------------- counting sort by dst ----------------
__global__ void fill0(float* __restrict__ p, int n4) {
    int i = blockIdx.x * 256 + threadIdx.x;
    if (i < n4) ((float4*)p)[i] = make_float4(0.f, 0.f, 0.f, 0.f);
}

__global__ void hist_k(const int* __restrict__ ei, int* __restrict__ cnt) {
    int e = blockIdx.x * 256 + threadIdx.x;
    if (e < NEDGE) atomicAdd(&cnt[ei[NEDGE + e]], 1);
}

__global__ void scan_k(const int* __restrict__ cnt, int* __restrict__ offs) {
    __shared__ int part[256];
    int t = threadIdx.x;
    int base = t * 64;
    int s = 0;
    for (int i = 0; i < 64; ++i) s += cnt[base + i];
    part[t] = s;
    __syncthreads();
    for (int off = 1; off < 256; off <<= 1) {
        int v = (t >= off) ? part[t - off] : 0;
        __syncthreads();
        part[t] += v;
        __syncthreads();
    }
    int r = part[t] - s;
    for (int i = 0; i < 64; ++i) { offs[base + i] = r; r += cnt[base + i]; }
    if (t == 255) offs[NATOM] = r;
}

__global__ void scatter_k(const int* __restrict__ ei, const int* __restrict__ offs,
                          int* __restrict__ cnt, int* __restrict__ perm) {
    int e = blockIdx.x * 256 + threadIdx.x;
    if (e >= NEDGE) return;
    int d = ei[NEDGE + e];
    int r = atomicAdd(&cnt[d], 1);
    perm[offs[d] + r] = e;
}

__global__ void gather_edges(const int* __restrict__ ei, const int* __restrict__ perm,
                             int* __restrict__ sSrc, int* __restrict__ sDst) {
    int j = blockIdx.x * 256 + threadIdx.x;
    if (j >= NEDGE) return;
    int e = perm[j];
    sSrc[j] = ei[e];
    sDst[j] = ei[NEDGE + e];
}

// ---------------- weight prep: transpose + fp16 hi/lo split ----------------
// W1T[i][fo][k] (k padded 50->64, zeros), W2T[i][fo][k]
__global__ void wprep(const float* __restrict__ Wf1, const float* __restrict__ Wf2,
                      _Float16* __restrict__ w1h, _Float16* __restrict__ w1l,
                      _Float16* __restrict__ w2h, _Float16* __restrict__ w2l) {
    int idx = blockIdx.x * 256 + threadIdx.x;
    if (idx < NI * 128 * 64) {
        int i = idx >> 13;
        int r = idx & 8191;
        int fo = r >> 6, k = r & 63;
        float v = (k < NG) ? Wf1[(size_t)i * NG * 128 + k * 128 + fo] : 0.0f;
        _Float16 hh = (_Float16)v;
        w1h[idx] = hh;
        w1l[idx] = (_Float16)(v - (float)hh);
        return;
    }
    int idx2 = idx - NI * 128 * 64;
    if (idx2 < NI * 128 * 128) {
        int i = idx2 >> 14;
        int r = idx2 & 16383;
        int fo = r >> 7, k = r & 127;
        float v = Wf2[(size_t)i * 128 * 128 + k * 128 + fo];
        _Float16 hh = (_Float16)v;
        w2h[idx2] = hh;
        w2l[idx2] = (_Float16)(v - (float)hh);
    }
}

// ---------------- embedding gather ----------------
__global__ void embed_k(const int* __restrict__ z, const float* __restrict__ emb,
                        float* __restrict__ h) {
    int tid = blockIdx.x * 256 + threadIdx.x;
    int n = tid >> 7, f = tid & 127;
    h[tid] = emb[z[n] * HID + f];
}

// ---------------- node GEMM (fp32, unchanged) ----------------
__launch_bounds__(256)
__global__ void gemm_node(const float* __restrict__ A, const float* __restrict__ B,
                          const float* __restrict__ bias, const float* __restrict__ res,
                          float* __restrict__ Cout, int do_ssp) {
    __shared__ float at[128 * 68];
    __shared__ float bt[32 * 128];
    int t = threadIdx.x;
    int mb = blockIdx.x * 64;
    for (int i = t; i < 64 * 32; i += 256) {
        int r = i >> 5, kq = i & 31;
        float4 v = *(const float4*)&A[(size_t)(mb + r) * HID + kq * 4];
        at[(kq*4+0)*68 + r] = v.x;
        at[(kq*4+1)*68 + r] = v.y;
        at[(kq*4+2)*68 + r] = v.z;
        at[(kq*4+3)*68 + r] = v.w;
    }
    int tm = t & 15, tf = t >> 4;
    int m0 = tm * 4, f0 = tf * 8;
    float bv[8];
    #pragma unroll
    for (int j = 0; j < 8; ++j) bv[j] = bias ? bias[f0 + j] : 0.0f;
    float acc[4][8];
    #pragma unroll
    for (int a = 0; a < 4; ++a)
        #pragma unroll
        for (int j = 0; j < 8; ++j) acc[a][j] = 0.0f;

    for (int c = 0; c < 4; ++c) {
        __syncthreads();
        for (int i = t; i < 32 * 32; i += 256) {
            int kk = i >> 5, c4 = i & 31;
            *(float4*)&bt[kk*128 + c4*4] = *(const float4*)&B[(size_t)(c*32 + kk)*128 + c4*4];
        }
        __syncthreads();
        #pragma unroll
        for (int kk = 0; kk < 32; ++kk) {
            int k = c * 32 + kk;
            float4 a4 = *(const float4*)&at[k*68 + m0];
            float aa[4] = {a4.x, a4.y, a4.z, a4.w};
            float4 b0 = *(const float4*)&bt[kk*128 + f0];
            float4 b1 = *(const float4*)&bt[kk*128 + f0 + 4];
            float bb[8] = {b0.x, b0.y, b0.z, b0.w, b1.x, b1.y, b1.z, b1.w};
            #pragma unroll
            for (int a = 0; a < 4; ++a)
                #pragma unroll
                for (int j = 0; j < 8; ++j)
                    acc[a][j] = fmaf(aa[a], bb[j], acc[a][j]);
        }
    }
    #pragma unroll
    for (int a = 0; a < 4; ++a) {
        size_t row = (size_t)(mb + m0 + a);
        float o[8];
        #pragma unroll
        for (int j = 0; j < 8; ++j) {
            float v = acc[a][j] + bv[j];
            o[j] = do_ssp ? ssp_f(v) : v;
        }
        if (res) {
            float4 r0 = *(const float4*)&res[row*128 + f0];
            float4 r1 = *(const float4*)&res[row*128 + f0 + 4];
            o[0]+=r0.x; o[1]+=r0.y; o[2]+=r0.z; o[3]+=r0.w;
            o[4]+=r1.x; o[5]+=r1.y; o[6]+=r1.z; o[7]+=r1.w;
        }
        *(float4*)&Cout[row*128 + f0]     = make_float4(o[0],o[1],o[2],o[3]);
        *(float4*)&Cout[row*128 + f0 + 4] = make_float4(o[4],o[5],o[6],o[7]);
    }
}

// ---------------- fused edge filter: MFMA fp16 hi/lo split ----------------
// per block: 64 sorted edges. GEMMs computed transposed: C[m=filter][n=edge].
// wave wv owns filters wv*32..wv*32+31 (2 m-tiles) x all 64 edges (4 n-tiles).
#define EA_LDW 72
#define W1_LDW 72
#define T1_LDW 136
#define MROW 132

__launch_bounds__(256)
__global__ void edge_filter(const float* __restrict__ pos, const float* __restrict__ x,
                            float* __restrict__ agg,
                            const int* __restrict__ sSrc, const int* __restrict__ sDst,
                            const _Float16* __restrict__ w1h, const _Float16* __restrict__ w1l,
                            const _Float16* __restrict__ w2h, const _Float16* __restrict__ w2l,
                            const float* __restrict__ bf1, const float* __restrict__ bf2) {
    __shared__ __align__(16) unsigned char smem[55296];
    __shared__ float dL[64];
    __shared__ float cL[64];
    __shared__ int dstl[64];
    __shared__ int srcl[64];

    _Float16* eaH = (_Float16*)smem;               // [64][72]
    _Float16* eaL = (_Float16*)(smem + 9216);
    _Float16* W1H = (_Float16*)(smem + 18432);     // [128][72]
    _Float16* W1L = (_Float16*)(smem + 36864);
    _Float16* t1H = (_Float16*)(smem + 18432);     // [64][136] (overlays W1)
    _Float16* t1L = (_Float16*)(smem + 35840);
    _Float16* w2H = (_Float16*)(smem);             // [128][32] chunk (overlays ea)
    _Float16* w2L = (_Float16*)(smem + 8192);
    float*    msg = (float*)smem;                  // [64][132] (overlays all)

    int t = threadIdx.x;
    int eb = blockIdx.x * 64;
    int wv = t >> 6, lane = t & 63;
    int l15 = lane & 15, quad = lane >> 4;

    // phase 0a: per-edge distance, cutoff, src/dst
    if (t < 64) {
        int e = eb + t;
        int s = sSrc[e], dd = sDst[e];
        srcl[t] = s; dstl[t] = dd;
        float dx = pos[3*s]   - pos[3*dd];
        float dy = pos[3*s+1] - pos[3*dd+1];
        float dz = pos[3*s+2] - pos[3*dd+2];
        float d = sqrtf(dx*dx + dy*dy + dz*dz);
        dL[t] = d;
        cL[t] = 0.5f * (cosf(d * 0.31415926535897931f) + 1.0f);
    }
    // stage W1T hi/lo (independent of phase 0a)
    for (int i = t; i < 1024; i += 256) {
        int r = i >> 3, seg = i & 7;
        *(h8_t*)&W1H[r*W1_LDW + seg*8] = *(const h8_t*)&w1h[r*64 + seg*8];
        *(h8_t*)&W1L[r*W1_LDW + seg*8] = *(const h8_t*)&w1l[r*64 + seg*8];
    }
    __syncthreads();
    // phase 0b: gaussians directly into LDS, hi/lo split (k padded to 64)
    const float delta = 10.0f / 49.0f;
    const float coeff = -0.5f / (delta * delta);
    for (int i = t; i < 4096; i += 256) {
        int el = i >> 6, g = i & 63;
        float v = 0.0f;
        if (g < NG) { float u = dL[el] - (float)g * delta; v = expf(coeff * u * u); }
        _Float16 hh = (_Float16)v;
        eaH[el*EA_LDW + g] = hh;
        eaL[el*EA_LDW + g] = (_Float16)(v - (float)hh);
    }
    __syncthreads();

    // bias fragments (4 consecutive filters per lane per m-tile)
    int fq = wv*32 + quad*4;
    f4_t b1v[2], b2v[2];
    b1v[0] = *(const f4_t*)&bf1[fq];  b1v[1] = *(const f4_t*)&bf1[fq + 16];
    b2v[0] = *(const f4_t*)&bf2[fq];  b2v[1] = *(const f4_t*)&bf2[fq + 16];

    // ---- GEMM1: t1^T = W1T @ ea^T, K=64 ----
    f4_t acc1[2][4];
    #pragma unroll
    for (int m = 0; m < 2; ++m)
        #pragma unroll
        for (int n = 0; n < 4; ++n) acc1[m][n] = (f4_t)0.0f;

    #pragma unroll
    for (int kc = 0; kc < 2; ++kc) {
        int k0 = kc*32 + quad*8;
        h8_t a_h[2], a_l[2], b_h[4], b_l[4];
        #pragma unroll
        for (int m = 0; m < 2; ++m) {
            int fr = wv*32 + m*16 + l15;
            a_h[m] = *(const h8_t*)&W1H[fr*W1_LDW + k0];
            a_l[m] = *(const h8_t*)&W1L[fr*W1_LDW + k0];
        }
        #pragma unroll
        for (int n = 0; n < 4; ++n) {
            int er = n*16 + l15;
            b_h[n] = *(const h8_t*)&eaH[er*EA_LDW + k0];
            b_l[n] = *(const h8_t*)&eaL[er*EA_LDW + k0];
        }
        #pragma unroll
        for (int m = 0; m < 2; ++m)
            #pragma unroll
            for (int n = 0; n < 4; ++n) {
                acc1[m][n] = __builtin_amdgcn_mfma_f32_16x16x32_f16(a_h[m], b_h[n], acc1[m][n], 0, 0, 0);
                acc1[m][n] = __builtin_amdgcn_mfma_f32_16x16x32_f16(a_h[m], b_l[n], acc1[m][n], 0, 0, 0);
                acc1[m][n] = __builtin_amdgcn_mfma_f32_16x16x32_f16(a_l[m], b_h[n], acc1[m][n], 0, 0, 0);
            }
    }
    __syncthreads();   // done reading W1/ea

    // epilogue1: bias+ssp, hi/lo split, write t1[edge][filter]
    #pragma unroll
    for (int m = 0; m < 2; ++m)
        #pragma unroll
        for (int n = 0; n < 4; ++n) {
            int el = n*16 + l15;
            int fb = wv*32 + m*16 + quad*4;
            h4_t hh, ll;
            #pragma unroll
            for (int r = 0; r < 4; ++r) {
                float sv = ssp_f(acc1[m][n][r] + b1v[m][r]);
                _Float16 hx = (_Float16)sv;
                hh[r] = hx;
                ll[r] = (_Float16)(sv - (float)hx);
            }
            *(h4_t*)&t1H[el*T1_LDW + fb] = hh;
            *(h4_t*)&t1L[el*T1_LDW + fb] = ll;
        }

    // ---- GEMM2: filt^T = W2T @ t1^T, K=128 (4 chunks of 32) ----
    f4_t acc2[2][4];
    #pragma unroll
    for (int m = 0; m < 2; ++m)
        #pragma unroll
        for (int n = 0; n < 4; ++n) acc2[m][n] = (f4_t)0.0f;

    for (int kc = 0; kc < 4; ++kc) {
        __syncthreads();
        for (int i = t; i < 512; i += 256) {
            int r = i >> 2, seg = i & 3;
            *(h8_t*)&w2H[r*32 + seg*8] = *(const h8_t*)&w2h[r*128 + kc*32 + seg*8];
            *(h8_t*)&w2L[r*32 + seg*8] = *(const h8_t*)&w2l[r*128 + kc*32 + seg*8];
        }
        __syncthreads();
        int kq = quad*8;
        h8_t a_h[2], a_l[2];
        #pragma unroll
        for (int m = 0; m < 2; ++m) {
            int fr = wv*32 + m*16 + l15;
            a_h[m] = *(const h8_t*)&w2H[fr*32 + kq];
            a_l[m] = *(const h8_t*)&w2L[fr*32 + kq];
        }
        #pragma unroll
        for (int n = 0; n < 4; ++n) {
            int er = n*16 + l15;
            h8_t b_h = *(const h8_t*)&t1H[er*T1_LDW + kc*32 + kq];
            h8_t b_l = *(const h8_t*)&t1L[er*T1_LDW + kc*32 + kq];
            #pragma unroll
            for (int m = 0; m < 2; ++m) {
                acc2[m][n] = __builtin_amdgcn_mfma_f32_16x16x32_f16(a_h[m], b_h, acc2[m][n], 0, 0, 0);
                acc2[m][n] = __builtin_amdgcn_mfma_f32_16x16x32_f16(a_h[m], b_l, acc2[m][n], 0, 0, 0);
                acc2[m][n] = __builtin_amdgcn_mfma_f32_16x16x32_f16(a_l[m], b_h, acc2[m][n], 0, 0, 0);
            }
        }
    }
    __syncthreads();   // done reading t1/w2 chunks

    // epilogue2: *C, gather x[src], write msg[edge][filter]
    #pragma unroll
    for (int n = 0; n < 4; ++n) {
        int el = n*16 + l15;
        float ce = cL[el];
        int s = srcl[el];
        #pragma unroll
        for (int m = 0; m < 2; ++m) {
            int fb = wv*32 + m*16 + quad*4;
            f4_t xr = *(const f4_t*)&x[(size_t)s * HID + fb];
            f4_t o;
            #pragma unroll
            for (int r = 0; r < 4; ++r)
                o[r] = (acc2[m][n][r] + b2v[m][r]) * ce * xr[r];
            *(f4_t*)&msg[el*MROW + fb] = o;
        }
    }
    __syncthreads();

    // segmented reduction over sorted dst
    int f = t & 127, hf = t >> 7;
    int ib = hf * 32;
    float run = 0.0f;
    int cur = dstl[ib];
    for (int i = ib; i < ib + 32; ++i) {
        int dnow = dstl[i];
        if (dnow != cur) {
            atomicAdd(&agg[(size_t)cur * HID + f], run);
            run = 0.0f;
            cur = dnow;
        }
        run += msg[i*MROW + f];
    }
    atomicAdd(&agg[(size_t)cur * HID + f], run);
}

// ---------------- readout ----------------
__launch_bounds__(256)
__global__ void readout1(const float* __restrict__ h, const float* __restrict__ Wo1,
                         const float* __restrict__ bo1, const float* __restrict__ Wo2,
                         const float* __restrict__ bo2, float* __restrict__ accum) {
    __shared__ float w1[128 * 64];
    int t = threadIdx.x;
    for (int i = t; i < 128 * 16; i += 256)
        ((float4*)w1)[i] = ((const float4*)Wo1)[i];
    __syncthreads();
    int f = t & 63, a = t >> 6;
    int n = blockIdx.x * 4 + a;
    float acc = bo1[f];
    #pragma unroll 8
    for (int k = 0; k < 128; ++k)
        acc = fmaf(h[(size_t)n * HID + k], w1[k*64 + f], acc);
    float u = ssp_f(acc) * Wo2[f];
    #pragma unroll
    for (int off = 32; off > 0; off >>= 1)
        u += __shfl_down(u, off, 64);
    if (f == 0) atomicAdd(accum, u + bo2[0]);
}

__global__ void readout2(const float* __restrict__ accum, float* __restrict__ out) {
    out[0] = fmaxf(accum[0], 0.0f);
}

extern "C" void kernel_launch(void* const* d_in, const int* in_sizes, int n_in,
                              void* d_out, int out_size, void* d_ws, size_t ws_size,
                              hipStream_t stream) {
    const int*   z   = (const int*)d_in[0];
    const float* pos = (const float*)d_in[1];
    const int*   ei  = (const int*)d_in[2];
    const float* emb = (const float*)d_in[3];
    const float* Wf1 = (const float*)d_in[4];
    const float* bf1 = (const float*)d_in[5];
    const float* Wf2 = (const float*)d_in[6];
    const float* bf2 = (const float*)d_in[7];
    const float* Wl1 = (const float*)d_in[8];
    const float* Wl2 = (const float*)d_in[9];
    const float* bl2 = (const float*)d_in[10];
    const float* Wl  = (const float*)d_in[11];
    const float* bl  = (const float*)d_in[12];
    const float* Wo1 = (const float*)d_in[13];
    const float* bo1 = (const float*)d_in[14];
    const float* Wo2 = (const float*)d_in[15];
    const float* bo2 = (const float*)d_in[16];
    float* out = (float*)d_out;

    // workspace layout: fp16 weight planes first (16B aligned from base)
    _Float16* w1h = (_Float16*)d_ws;                       // 6*128*64
    _Float16* w1l = w1h + NI * 128 * 64;
    _Float16* w2h = w1l + NI * 128 * 64;                   // 6*128*128
    _Float16* w2l = w2h + NI * 128 * 128;
    float* h   = (float*)(w2l + NI * 128 * 128);           // N*HID
    float* x   = h   + (size_t)NATOM * HID;
    float* agg = x   + (size_t)NATOM * HID;
    float* tb  = agg + (size_t)NATOM * HID;
    float* accum = tb + (size_t)NATOM * HID;               // 4
    int* cnt  = (int*)(accum + 4);                         // N
    int* offs = cnt + NATOM;                               // N+4
    int* perm = offs + NATOM + 4;                          // E
    int* sSrc = perm + NEDGE;                              // E
    int* sDst = sSrc + NEDGE;                              // E

    // counting sort by dst
    fill0<<<NATOM/4/256, 256, 0, stream>>>((float*)cnt, NATOM/4);
    hist_k<<<NEDGE/256, 256, 0, stream>>>(ei, cnt);
    scan_k<<<1, 256, 0, stream>>>(cnt, offs);
    fill0<<<NATOM/4/256, 256, 0, stream>>>((float*)cnt, NATOM/4);
    scatter_k<<<NEDGE/256, 256, 0, stream>>>(ei, offs, cnt, perm);
    gather_edges<<<NEDGE/256, 256, 0, stream>>>(ei, perm, sSrc, sDst);

    wprep<<<(NI*128*64 + NI*128*128 + 255)/256, 256, 0, stream>>>(Wf1, Wf2, w1h, w1l, w2h, w2l);
    embed_k<<<(NATOM*HID)/256, 256, 0, stream>>>(z, emb, h);

    for (int i = 0; i < NI; ++i) {
        gemm_node<<<NATOM/64, 256, 0, stream>>>(h, Wl1 + (size_t)i*HID*HID, nullptr, nullptr, x, 0);
        fill0<<<(NATOM*HID/4)/256, 256, 0, stream>>>(agg, NATOM*HID/4);
        edge_filter<<<NEDGE/64, 256, 0, stream>>>(pos, x, agg, sSrc, sDst,
            w1h + (size_t)i*128*64, w1l + (size_t)i*128*64,
            w2h + (size_t)i*128*128, w2l + (size_t)i*128*128,
            bf1 + i*HID, bf2 + i*HID);
        gemm_node<<<NATOM/64, 256, 0, stream>>>(agg, Wl2 + (size_t)i*HID*HID, bl2 + i*HID, nullptr, tb, 1);
        gemm_node<<<NATOM/64, 256, 0, stream>>>(tb, Wl + (size_t)i*HID*HID, bl + i*HID, h, h, 0);
    }
    fill0<<<1, 256, 0, stream>>>(accum, 1);
    readout1<<<NATOM/4, 256, 0, stream>>>(h, Wo1, bo1, Wo2, bo2, accum);
    readout2<<<1, 1, 0, stream>>>(accum, out);
}

// Round 4
// 1297.968 us; speedup vs baseline: 5.0164x; 1.3147x over previous
//
#include <hip/hip_runtime.h>
#include <math.h>

#define NATOM 16384
#define NEDGE 262144
#define HID 128
#define NG 50
#define NI 6

typedef _Float16 h8_t __attribute__((ext_vector_type(8)));
typedef _Float16 h4_t __attribute__((ext_vector_type(4)));
typedef float    f4_t __attribute__((ext_vector_type(4)));

__device__ __forceinline__ float ssp_f(float v) {
    return fmaxf(v, 0.0f) + log1pf(expf(-fabsf(v))) - 0.69314718055994531f;
}

// ---------------- counting sort by dst ----------------
__global__ void fill0(float* __restrict__ p, int n4) {
    int i = blockIdx.x * 256 + threadIdx.x;
    if (i < n4) ((float4*)p)[i] = make_float4(0.f, 0.f, 0.f, 0.f);
}

__global__ void hist_k(const int* __restrict__ ei, int* __restrict__ cnt) {
    int e = blockIdx.x * 256 + threadIdx.x;
    if (e < NEDGE) atomicAdd(&cnt[ei[NEDGE + e]], 1);
}

__global__ void scan_k(const int* __restrict__ cnt, int* __restrict__ offs) {
    __shared__ int part[256];
    int t = threadIdx.x;
    int base = t * 64;
    int s = 0;
    for (int i = 0; i < 64; ++i) s += cnt[base + i];
    part[t] = s;
    __syncthreads();
    for (int off = 1; off < 256; off <<= 1) {
        int v = (t >= off) ? part[t - off] : 0;
        __syncthreads();
        part[t] += v;
        __syncthreads();
    }
    int r = part[t] - s;
    for (int i = 0; i < 64; ++i) { offs[base + i] = r; r += cnt[base + i]; }
    if (t == 255) offs[NATOM] = r;
}

__global__ void scatter_k(const int* __restrict__ ei, const int* __restrict__ offs,
                          int* __restrict__ cnt, int* __restrict__ perm) {
    int e = blockIdx.x * 256 + threadIdx.x;
    if (e >= NEDGE) return;
    int d = ei[NEDGE + e];
    int r = atomicAdd(&cnt[d], 1);
    perm[offs[d] + r] = e;
}

__global__ void gather_edges(const int* __restrict__ ei, const int* __restrict__ perm,
                             int* __restrict__ sSrc, int* __restrict__ sDst) {
    int j = blockIdx.x * 256 + threadIdx.x;
    if (j >= NEDGE) return;
    int e = perm[j];
    sSrc[j] = ei[e];
    sDst[j] = ei[NEDGE + e];
}

// ---------------- weight prep: transpose + fp16 hi/lo split ----------------
__global__ void wprep(const float* __restrict__ Wf1, const float* __restrict__ Wf2,
                      const float* __restrict__ Wl1, const float* __restrict__ Wl2,
                      const float* __restrict__ Wl,
                      _Float16* __restrict__ w1h, _Float16* __restrict__ w1l,
                      _Float16* __restrict__ w2h, _Float16* __restrict__ w2l,
                      _Float16* __restrict__ wnh, _Float16* __restrict__ wnl) {
    int idx = blockIdx.x * 256 + threadIdx.x;
    const int S1 = NI * 128 * 64, S2 = NI * 128 * 128;
    if (idx < S1) {
        int i = idx >> 13, r = idx & 8191, fo = r >> 6, k = r & 63;
        float v = (k < NG) ? Wf1[(size_t)i * NG * 128 + k * 128 + fo] : 0.0f;
        _Float16 hh = (_Float16)v;
        w1h[idx] = hh; w1l[idx] = (_Float16)(v - (float)hh);
        return;
    }
    idx -= S1;
    if (idx < S2) {
        int i = idx >> 14, r = idx & 16383, fo = r >> 7, k = r & 127;
        float v = Wf2[(size_t)i * 128 * 128 + k * 128 + fo];
        _Float16 hh = (_Float16)v;
        w2h[idx] = hh; w2l[idx] = (_Float16)(v - (float)hh);
        return;
    }
    idx -= S2;
    if (idx < 3 * S2) {
        int mi = idx >> 14;               // mat*NI + iter, 0..17
        int r = idx & 16383, fo = r >> 7, k = r & 127;
        int m = mi / NI, i = mi % NI;
        const float* W = (m == 0) ? Wl1 : (m == 1) ? Wl2 : Wl;
        float v = W[(size_t)i * 128 * 128 + k * 128 + fo];
        _Float16 hh = (_Float16)v;
        wnh[idx] = hh; wnl[idx] = (_Float16)(v - (float)hh);
    }
}

// ---------------- embedding gather ----------------
__global__ void embed_k(const int* __restrict__ z, const float* __restrict__ emb,
                        float* __restrict__ h) {
    int tid = blockIdx.x * 256 + threadIdx.x;
    int n = tid >> 7, f = tid & 127;
    h[tid] = emb[z[n] * HID + f];
}

// ---------------- node GEMM via MFMA fp16 hi/lo ----------------
// C[atom][outf] = A[atom][:] @ W ; computed as D[outf][atom] = Wt @ A^T
// block: 64 atoms, 4 waves; wave wv owns outf wv*32..+31 (2 m-tiles) x 4 n-tiles
__launch_bounds__(256)
__global__ void gemm_node_mfma(const float* __restrict__ A,
                               const _Float16* __restrict__ wth, const _Float16* __restrict__ wtl,
                               const float* __restrict__ bias, const float* __restrict__ res,
                               float* __restrict__ Cout, int do_ssp) {
    __shared__ _Float16 aH[64 * 136];
    __shared__ _Float16 aL[64 * 136];
    int t = threadIdx.x;
    int mb = blockIdx.x * 64;
    #pragma unroll
    for (int j = 0; j < 8; ++j) {
        int idx = t + j * 256;            // 64 rows x 32 f4-chunks
        int row = idx >> 5, c4 = idx & 31;
        f4_t v = *(const f4_t*)&A[(size_t)(mb + row) * HID + c4 * 4];
        h4_t hh, ll;
        #pragma unroll
        for (int r = 0; r < 4; ++r) {
            _Float16 hx = (_Float16)v[r];
            hh[r] = hx; ll[r] = (_Float16)(v[r] - (float)hx);
        }
        *(h4_t*)&aH[row * 136 + c4 * 4] = hh;
        *(h4_t*)&aL[row * 136 + c4 * 4] = ll;
    }
    __syncthreads();

    int wv = t >> 6, lane = t & 63, l15 = lane & 15, quad = lane >> 4;
    f4_t acc[2][4];
    #pragma unroll
    for (int m = 0; m < 2; ++m)
        #pragma unroll
        for (int n = 0; n < 4; ++n) acc[m][n] = (f4_t)0.0f;

    for (int kc = 0; kc < 4; ++kc) {
        int k0 = kc * 32 + quad * 8;
        h8_t a_h[2], a_l[2];
        #pragma unroll
        for (int m = 0; m < 2; ++m) {
            int fr = wv * 32 + m * 16 + l15;
            a_h[m] = *(const h8_t*)&wth[fr * 128 + k0];
            a_l[m] = *(const h8_t*)&wtl[fr * 128 + k0];
        }
        #pragma unroll
        for (int n = 0; n < 4; ++n) {
            int er = n * 16 + l15;
            h8_t b_h = *(const h8_t*)&aH[er * 136 + k0];
            h8_t b_l = *(const h8_t*)&aL[er * 136 + k0];
            #pragma unroll
            for (int m = 0; m < 2; ++m) {
                acc[m][n] = __builtin_amdgcn_mfma_f32_16x16x32_f16(a_h[m], b_h, acc[m][n], 0, 0, 0);
                acc[m][n] = __builtin_amdgcn_mfma_f32_16x16x32_f16(a_h[m], b_l, acc[m][n], 0, 0, 0);
                acc[m][n] = __builtin_amdgcn_mfma_f32_16x16x32_f16(a_l[m], b_h, acc[m][n], 0, 0, 0);
            }
        }
    }

    int fq = wv * 32 + quad * 4;
    f4_t bv[2];
    if (bias) { bv[0] = *(const f4_t*)&bias[fq]; bv[1] = *(const f4_t*)&bias[fq + 16]; }
    else      { bv[0] = (f4_t)0.0f; bv[1] = (f4_t)0.0f; }

    #pragma unroll
    for (int n = 0; n < 4; ++n) {
        int el = n * 16 + l15;
        size_t row = (size_t)(mb + el);
        #pragma unroll
        for (int m = 0; m < 2; ++m) {
            int fb = wv * 32 + m * 16 + quad * 4;
            f4_t o;
            #pragma unroll
            for (int r = 0; r < 4; ++r) {
                float v = acc[m][n][r] + bv[m][r];
                o[r] = do_ssp ? ssp_f(v) : v;
            }
            if (res) {
                f4_t rv = *(const f4_t*)&res[row * 128 + fb];
                #pragma unroll
                for (int r = 0; r < 4; ++r) o[r] += rv[r];
            }
            *(f4_t*)&Cout[row * 128 + fb] = o;
        }
    }
}

// ---------------- fused edge filter: MFMA, weights direct-from-global ----------------
#define EA_LDW 72
#define T1_LDW 136
#define MROW 132

__launch_bounds__(256)
__global__ void edge_filter(const float* __restrict__ pos, const float* __restrict__ x,
                            float* __restrict__ agg,
                            const int* __restrict__ sSrc, const int* __restrict__ sDst,
                            const _Float16* __restrict__ w1h, const _Float16* __restrict__ w1l,
                            const _Float16* __restrict__ w2h, const _Float16* __restrict__ w2l,
                            const float* __restrict__ bf1, const float* __restrict__ bf2) {
    __shared__ __align__(16) unsigned char smem[53248];
    __shared__ float dL[64];
    __shared__ float cL[64];
    __shared__ int dstl[64];
    __shared__ int srcl[64];

    _Float16* eaH = (_Float16*)smem;               // [64][72]
    _Float16* eaL = (_Float16*)(smem + 9216);
    _Float16* t1H = (_Float16*)(smem + 18432);     // [64][136]
    _Float16* t1L = (_Float16*)(smem + 35840);
    float*    msg = (float*)smem;                  // [64][132], overlays ea/t1H after GEMM2

    int t = threadIdx.x;
    int eb = blockIdx.x * 64;
    int wv = t >> 6, lane = t & 63;
    int l15 = lane & 15, quad = lane >> 4;

    // phase 0a: per-edge distance, cutoff, src/dst
    if (t < 64) {
        int e = eb + t;
        int s = sSrc[e], dd = sDst[e];
        srcl[t] = s; dstl[t] = dd;
        float dx = pos[3*s]   - pos[3*dd];
        float dy = pos[3*s+1] - pos[3*dd+1];
        float dz = pos[3*s+2] - pos[3*dd+2];
        float d = sqrtf(dx*dx + dy*dy + dz*dz);
        dL[t] = d;
        cL[t] = 0.5f * (cosf(d * 0.31415926535897931f) + 1.0f);
    }
    __syncthreads();
    // phase 0b: gaussians into LDS, hi/lo split (k padded to 64)
    const float delta = 10.0f / 49.0f;
    const float coeff = -0.5f / (delta * delta);
    for (int i = t; i < 4096; i += 256) {
        int el = i >> 6, g = i & 63;
        float v = 0.0f;
        if (g < NG) { float u = dL[el] - (float)g * delta; v = expf(coeff * u * u); }
        _Float16 hh = (_Float16)v;
        eaH[el*EA_LDW + g] = hh;
        eaL[el*EA_LDW + g] = (_Float16)(v - (float)hh);
    }
    __syncthreads();

    int fq = wv*32 + quad*4;
    f4_t b1v[2], b2v[2];
    b1v[0] = *(const f4_t*)&bf1[fq];  b1v[1] = *(const f4_t*)&bf1[fq + 16];
    b2v[0] = *(const f4_t*)&bf2[fq];  b2v[1] = *(const f4_t*)&bf2[fq + 16];

    // ---- GEMM1: t1^T = W1T @ ea^T, K=64; W1 frags straight from global (L2) ----
    f4_t acc1[2][4];
    #pragma unroll
    for (int m = 0; m < 2; ++m)
        #pragma unroll
        for (int n = 0; n < 4; ++n) acc1[m][n] = (f4_t)0.0f;

    #pragma unroll
    for (int kc = 0; kc < 2; ++kc) {
        int k0 = kc*32 + quad*8;
        h8_t a_h[2], a_l[2], b_h[4], b_l[4];
        #pragma unroll
        for (int m = 0; m < 2; ++m) {
            int fr = wv*32 + m*16 + l15;
            a_h[m] = *(const h8_t*)&w1h[fr*64 + k0];
            a_l[m] = *(const h8_t*)&w1l[fr*64 + k0];
        }
        #pragma unroll
        for (int n = 0; n < 4; ++n) {
            int er = n*16 + l15;
            b_h[n] = *(const h8_t*)&eaH[er*EA_LDW + k0];
            b_l[n] = *(const h8_t*)&eaL[er*EA_LDW + k0];
        }
        #pragma unroll
        for (int m = 0; m < 2; ++m)
            #pragma unroll
            for (int n = 0; n < 4; ++n) {
                acc1[m][n] = __builtin_amdgcn_mfma_f32_16x16x32_f16(a_h[m], b_h[n], acc1[m][n], 0, 0, 0);
                acc1[m][n] = __builtin_amdgcn_mfma_f32_16x16x32_f16(a_h[m], b_l[n], acc1[m][n], 0, 0, 0);
                acc1[m][n] = __builtin_amdgcn_mfma_f32_16x16x32_f16(a_l[m], b_h[n], acc1[m][n], 0, 0, 0);
            }
    }

    // epilogue1: bias+ssp, hi/lo split, write t1[edge][filter] (own region, no overlay)
    #pragma unroll
    for (int m = 0; m < 2; ++m)
        #pragma unroll
        for (int n = 0; n < 4; ++n) {
            int el = n*16 + l15;
            int fb = wv*32 + m*16 + quad*4;
            h4_t hh, ll;
            #pragma unroll
            for (int r = 0; r < 4; ++r) {
                float sv = ssp_f(acc1[m][n][r] + b1v[m][r]);
                _Float16 hx = (_Float16)sv;
                hh[r] = hx;
                ll[r] = (_Float16)(sv - (float)hx);
            }
            *(h4_t*)&t1H[el*T1_LDW + fb] = hh;
            *(h4_t*)&t1L[el*T1_LDW + fb] = ll;
        }
    __syncthreads();   // t1 complete, visible to all waves

    // ---- GEMM2: filt^T = W2T @ t1^T, K=128; W2 frags straight from global ----
    f4_t acc2[2][4];
    #pragma unroll
    for (int m = 0; m < 2; ++m)
        #pragma unroll
        for (int n = 0; n < 4; ++n) acc2[m][n] = (f4_t)0.0f;

    for (int kc = 0; kc < 4; ++kc) {
        int k0 = kc*32 + quad*8;
        h8_t a_h[2], a_l[2];
        #pragma unroll
        for (int m = 0; m < 2; ++m) {
            int fr = wv*32 + m*16 + l15;
            a_h[m] = *(const h8_t*)&w2h[fr*128 + k0];
            a_l[m] = *(const h8_t*)&w2l[fr*128 + k0];
        }
        #pragma unroll
        for (int n = 0; n < 4; ++n) {
            int er = n*16 + l15;
            h8_t b_h = *(const h8_t*)&t1H[er*T1_LDW + k0];
            h8_t b_l = *(const h8_t*)&t1L[er*T1_LDW + k0];
            #pragma unroll
            for (int m = 0; m < 2; ++m) {
                acc2[m][n] = __builtin_amdgcn_mfma_f32_16x16x32_f16(a_h[m], b_h, acc2[m][n], 0, 0, 0);
                acc2[m][n] = __builtin_amdgcn_mfma_f32_16x16x32_f16(a_h[m], b_l, acc2[m][n], 0, 0, 0);
                acc2[m][n] = __builtin_amdgcn_mfma_f32_16x16x32_f16(a_l[m], b_h, acc2[m][n], 0, 0, 0);
            }
        }
    }
    __syncthreads();   // t1 dead; msg may overlay

    // epilogue2: *C, gather x[src], write msg[edge][filter]
    #pragma unroll
    for (int n = 0; n < 4; ++n) {
        int el = n*16 + l15;
        float ce = cL[el];
        int s = srcl[el];
        #pragma unroll
        for (int m = 0; m < 2; ++m) {
            int fb = wv*32 + m*16 + quad*4;
            f4_t xr = *(const f4_t*)&x[(size_t)s * HID + fb];
            f4_t o;
            #pragma unroll
            for (int r = 0; r < 4; ++r)
                o[r] = (acc2[m][n][r] + b2v[m][r]) * ce * xr[r];
            *(f4_t*)&msg[el*MROW + fb] = o;
        }
    }
    __syncthreads();

    // segmented reduction over sorted dst
    int f = t & 127, hf = t >> 7;
    int ib = hf * 32;
    float run = 0.0f;
    int cur = dstl[ib];
    for (int i = ib; i < ib + 32; ++i) {
        int dnow = dstl[i];
        if (dnow != cur) {
            atomicAdd(&agg[(size_t)cur * HID + f], run);
            run = 0.0f;
            cur = dnow;
        }
        run += msg[i*MROW + f];
    }
    atomicAdd(&agg[(size_t)cur * HID + f], run);
}

// ---------------- readout: 256 blocks, deferred reduce, 1 atomic/block ----------------
__launch_bounds__(256)
__global__ void readout1(const float* __restrict__ h, const float* __restrict__ Wo1,
                         const float* __restrict__ bo1, const float* __restrict__ Wo2,
                         const float* __restrict__ bo2, float* __restrict__ accum) {
    __shared__ float w1[128 * 64];
    __shared__ float part[4];
    int t = threadIdx.x;
    for (int i = t; i < 128 * 16; i += 256)
        ((float4*)w1)[i] = ((const float4*)Wo1)[i];
    __syncthreads();
    int f = t & 63, wv = t >> 6;
    float b = bo1[f], w2v = Wo2[f];
    float lsum = 0.0f;
    for (int a = 0; a < 16; ++a) {
        int n = blockIdx.x * 64 + wv * 16 + a;
        const float* hr = &h[(size_t)n * HID];
        float acc = b;
        #pragma unroll 16
        for (int k = 0; k < 128; ++k)
            acc = fmaf(hr[k], w1[k*64 + f], acc);
        lsum += ssp_f(acc) * w2v;
    }
    #pragma unroll
    for (int off = 32; off > 0; off >>= 1)
        lsum += __shfl_down(lsum, off, 64);
    if (f == 0) part[wv] = lsum;
    __syncthreads();
    if (t == 0)
        atomicAdd(accum, part[0] + part[1] + part[2] + part[3] + 64.0f * bo2[0]);
}

__global__ void readout2(const float* __restrict__ accum, float* __restrict__ out) {
    out[0] = fmaxf(accum[0], 0.0f);
}

extern "C" void kernel_launch(void* const* d_in, const int* in_sizes, int n_in,
                              void* d_out, int out_size, void* d_ws, size_t ws_size,
                              hipStream_t stream) {
    const int*   z   = (const int*)d_in[0];
    const float* pos = (const float*)d_in[1];
    const int*   ei  = (const int*)d_in[2];
    const float* emb = (const float*)d_in[3];
    const float* Wf1 = (const float*)d_in[4];
    const float* bf1 = (const float*)d_in[5];
    const float* Wf2 = (const float*)d_in[6];
    const float* bf2 = (const float*)d_in[7];
    const float* Wl1 = (const float*)d_in[8];
    const float* Wl2 = (const float*)d_in[9];
    const float* bl2 = (const float*)d_in[10];
    const float* Wl  = (const float*)d_in[11];
    const float* bl  = (const float*)d_in[12];
    const float* Wo1 = (const float*)d_in[13];
    const float* bo1 = (const float*)d_in[14];
    const float* Wo2 = (const float*)d_in[15];
    const float* bo2 = (const float*)d_in[16];
    float* out = (float*)d_out;

    _Float16* w1h = (_Float16*)d_ws;                       // NI*8192
    _Float16* w1l = w1h + NI * 8192;
    _Float16* w2h = w1l + NI * 8192;                       // NI*16384
    _Float16* w2l = w2h + NI * 16384;
    _Float16* wnh = w2l + NI * 16384;                      // 3*NI*16384
    _Float16* wnl = wnh + 3 * NI * 16384;
    float* h   = (float*)(wnl + 3 * NI * 16384);
    float* x   = h   + (size_t)NATOM * HID;
    float* agg = x   + (size_t)NATOM * HID;
    float* tb  = agg + (size_t)NATOM * HID;
    float* accum = tb + (size_t)NATOM * HID;               // 4
    int* cnt  = (int*)(accum + 4);                         // N
    int* offs = cnt + NATOM;                               // N+4
    int* perm = offs + NATOM + 4;                          // E
    int* sSrc = perm + NEDGE;                              // E
    int* sDst = sSrc + NEDGE;                              // E

    fill0<<<NATOM/4/256, 256, 0, stream>>>((float*)cnt, NATOM/4);
    hist_k<<<NEDGE/256, 256, 0, stream>>>(ei, cnt);
    scan_k<<<1, 256, 0, stream>>>(cnt, offs);
    fill0<<<NATOM/4/256, 256, 0, stream>>>((float*)cnt, NATOM/4);
    scatter_k<<<NEDGE/256, 256, 0, stream>>>(ei, offs, cnt, perm);
    gather_edges<<<NEDGE/256, 256, 0, stream>>>(ei, perm, sSrc, sDst);

    wprep<<<(NI*8192 + NI*16384 + 3*NI*16384)/256, 256, 0, stream>>>(
        Wf1, Wf2, Wl1, Wl2, Wl, w1h, w1l, w2h, w2l, wnh, wnl);
    embed_k<<<(NATOM*HID)/256, 256, 0, stream>>>(z, emb, h);

    for (int i = 0; i < NI; ++i) {
        gemm_node_mfma<<<256, 256, 0, stream>>>(h, wnh + (size_t)(0*NI+i)*16384,
            wnl + (size_t)(0*NI+i)*16384, nullptr, nullptr, x, 0);
        fill0<<<(NATOM*HID/4)/256, 256, 0, stream>>>(agg, NATOM*HID/4);
        edge_filter<<<NEDGE/64, 256, 0, stream>>>(pos, x, agg, sSrc, sDst,
            w1h + (size_t)i*8192, w1l + (size_t)i*8192,
            w2h + (size_t)i*16384, w2l + (size_t)i*16384,
            bf1 + i*HID, bf2 + i*HID);
        gemm_node_mfma<<<256, 256, 0, stream>>>(agg, wnh + (size_t)(1*NI+i)*16384,
            wnl + (size_t)(1*NI+i)*16384, bl2 + i*HID, nullptr, tb, 1);
        gemm_node_mfma<<<256, 256, 0, stream>>>(tb, wnh + (size_t)(2*NI+i)*16384,
            wnl + (size_t)(2*NI+i)*16384, bl + i*HID, h, h, 0);
    }
    fill0<<<1, 256, 0, stream>>>(accum, 1);
    readout1<<<NATOM/64, 256, 0, stream>>>(h, Wo1, bo1, Wo2, bo2, accum);
    readout2<<<1, 1, 0, stream>>>(accum, out);
}

// Round 5
// 916.744 us; speedup vs baseline: 7.1025x; 1.4158x over previous
//
#include <hip/hip_runtime.h>
#include <math.h>

#define NATOM 16384
#define NEDGE 262144
#define HID 128
#define NG 50
#define NI 6

typedef _Float16 h8_t __attribute__((ext_vector_type(8)));
typedef _Float16 h4_t __attribute__((ext_vector_type(4)));
typedef float    f4_t __attribute__((ext_vector_type(4)));

// fast shifted-softplus: v_exp_f32 / v_log_f32 (~1ulp), error ~1e-7 abs
__device__ __forceinline__ float ssp_f(float v) {
    float e = __expf(-fabsf(v));
    return fmaxf(v, 0.0f) + __logf(1.0f + e) - 0.69314718055994531f;
}

// ---------------- counting sort by dst ----------------
__global__ void fill0(float* __restrict__ p, int n4) {
    int i = blockIdx.x * 256 + threadIdx.x;
    if (i < n4) ((float4*)p)[i] = make_float4(0.f, 0.f, 0.f, 0.f);
}

__global__ void hist_k(const int* __restrict__ ei, int* __restrict__ cnt) {
    int e = blockIdx.x * 256 + threadIdx.x;
    if (e < NEDGE) atomicAdd(&cnt[ei[NEDGE + e]], 1);
}

__global__ void scan_k(const int* __restrict__ cnt, int* __restrict__ offs) {
    __shared__ int part[256];
    int t = threadIdx.x;
    int base = t * 64;
    int s = 0;
    for (int i = 0; i < 64; ++i) s += cnt[base + i];
    part[t] = s;
    __syncthreads();
    for (int off = 1; off < 256; off <<= 1) {
        int v = (t >= off) ? part[t - off] : 0;
        __syncthreads();
        part[t] += v;
        __syncthreads();
    }
    int r = part[t] - s;
    for (int i = 0; i < 64; ++i) { offs[base + i] = r; r += cnt[base + i]; }
    if (t == 255) offs[NATOM] = r;
}

__global__ void scatter_k(const int* __restrict__ ei, const int* __restrict__ offs,
                          int* __restrict__ cnt, int* __restrict__ sSrc, int* __restrict__ sDst) {
    int e = blockIdx.x * 256 + threadIdx.x;
    if (e >= NEDGE) return;
    int d = ei[NEDGE + e];
    int r = atomicAdd(&cnt[d], 1);
    int j = offs[d] + r;
    sSrc[j] = ei[e];
    sDst[j] = d;
}

// ---------------- edge precompute (once): gaussians hi/lo, cutoff ----------------
// eaH/eaL edge-major [e][64] (50 gaussians + zero pad) so a 64-edge tile is contiguous
__global__ void edge_pre(const float* __restrict__ pos,
                         const int* __restrict__ sSrc, const int* __restrict__ sDst,
                         _Float16* __restrict__ eaH, _Float16* __restrict__ eaL,
                         float* __restrict__ Cb) {
    int j = blockIdx.x * 256 + threadIdx.x;
    if (j >= NEDGE) return;
    int s = sSrc[j], dd = sDst[j];
    float dx = pos[3*s]   - pos[3*dd];
    float dy = pos[3*s+1] - pos[3*dd+1];
    float dz = pos[3*s+2] - pos[3*dd+2];
    float d = sqrtf(dx*dx + dy*dy + dz*dz);
    Cb[j] = 0.5f * (cosf(d * 0.31415926535897931f) + 1.0f);
    const float delta = 10.0f / 49.0f;
    const float coeff = -0.5f / (delta * delta);
    #pragma unroll
    for (int gq = 0; gq < 8; ++gq) {
        h8_t hv, lv;
        #pragma unroll
        for (int r = 0; r < 8; ++r) {
            int g = gq * 8 + r;
            float v = 0.0f;
            if (g < NG) { float u = d - (float)g * delta; v = __expf(coeff * u * u); }
            _Float16 hh = (_Float16)v;
            hv[r] = hh;
            lv[r] = (_Float16)(v - (float)hh);
        }
        *(h8_t*)&eaH[(size_t)j * 64 + gq * 8] = hv;
        *(h8_t*)&eaL[(size_t)j * 64 + gq * 8] = lv;
    }
}

// ---------------- weight prep: transpose + fp16 hi/lo split ----------------
__global__ void wprep(const float* __restrict__ Wf1, const float* __restrict__ Wf2,
                      const float* __restrict__ Wl1, const float* __restrict__ Wl2,
                      const float* __restrict__ Wl,
                      _Float16* __restrict__ w1h, _Float16* __restrict__ w1l,
                      _Float16* __restrict__ w2h, _Float16* __restrict__ w2l,
                      _Float16* __restrict__ wnh, _Float16* __restrict__ wnl) {
    int idx = blockIdx.x * 256 + threadIdx.x;
    const int S1 = NI * 128 * 64, S2 = NI * 128 * 128;
    if (idx < S1) {
        int i = idx >> 13, r = idx & 8191, fo = r >> 6, k = r & 63;
        float v = (k < NG) ? Wf1[(size_t)i * NG * 128 + k * 128 + fo] : 0.0f;
        _Float16 hh = (_Float16)v;
        w1h[idx] = hh; w1l[idx] = (_Float16)(v - (float)hh);
        return;
    }
    idx -= S1;
    if (idx < S2) {
        int i = idx >> 14, r = idx & 16383, fo = r >> 7, k = r & 127;
        float v = Wf2[(size_t)i * 128 * 128 + k * 128 + fo];
        _Float16 hh = (_Float16)v;
        w2h[idx] = hh; w2l[idx] = (_Float16)(v - (float)hh);
        return;
    }
    idx -= S2;
    if (idx < 3 * S2) {
        int mi = idx >> 14;
        int r = idx & 16383, fo = r >> 7, k = r & 127;
        int m = mi / NI, i = mi % NI;
        const float* W = (m == 0) ? Wl1 : (m == 1) ? Wl2 : Wl;
        float v = W[(size_t)i * 128 * 128 + k * 128 + fo];
        _Float16 hh = (_Float16)v;
        wnh[idx] = hh; wnl[idx] = (_Float16)(v - (float)hh);
    }
}

// ---------------- embedding gather ----------------
__global__ void embed_k(const int* __restrict__ z, const float* __restrict__ emb,
                        float* __restrict__ h) {
    int tid = blockIdx.x * 256 + threadIdx.x;
    int n = tid >> 7, f = tid & 127;
    h[tid] = emb[z[n] * HID + f];
}

// ---------------- node GEMM via MFMA fp16 hi/lo (single, for lin1) ----------------
__launch_bounds__(256)
__global__ void gemm_node_mfma(const float* __restrict__ A,
                               const _Float16* __restrict__ wth, const _Float16* __restrict__ wtl,
                               float* __restrict__ Cout) {
    __shared__ _Float16 aH[64 * 136];
    __shared__ _Float16 aL[64 * 136];
    int t = threadIdx.x;
    int mb = blockIdx.x * 64;
    #pragma unroll
    for (int j = 0; j < 8; ++j) {
        int idx = t + j * 256;
        int row = idx >> 5, c4 = idx & 31;
        f4_t v = *(const f4_t*)&A[(size_t)(mb + row) * HID + c4 * 4];
        h4_t hh, ll;
        #pragma unroll
        for (int r = 0; r < 4; ++r) {
            _Float16 hx = (_Float16)v[r];
            hh[r] = hx; ll[r] = (_Float16)(v[r] - (float)hx);
        }
        *(h4_t*)&aH[row * 136 + c4 * 4] = hh;
        *(h4_t*)&aL[row * 136 + c4 * 4] = ll;
    }
    __syncthreads();

    int wv = t >> 6, lane = t & 63, l15 = lane & 15, quad = lane >> 4;
    f4_t acc[2][4];
    #pragma unroll
    for (int m = 0; m < 2; ++m)
        #pragma unroll
        for (int n = 0; n < 4; ++n) acc[m][n] = (f4_t)0.0f;

    for (int kc = 0; kc < 4; ++kc) {
        int k0 = kc * 32 + quad * 8;
        h8_t a_h[2], a_l[2];
        #pragma unroll
        for (int m = 0; m < 2; ++m) {
            int fr = wv * 32 + m * 16 + l15;
            a_h[m] = *(const h8_t*)&wth[fr * 128 + k0];
            a_l[m] = *(const h8_t*)&wtl[fr * 128 + k0];
        }
        #pragma unroll
        for (int n = 0; n < 4; ++n) {
            int er = n * 16 + l15;
            h8_t b_h = *(const h8_t*)&aH[er * 136 + k0];
            h8_t b_l = *(const h8_t*)&aL[er * 136 + k0];
            #pragma unroll
            for (int m = 0; m < 2; ++m) {
                acc[m][n] = __builtin_amdgcn_mfma_f32_16x16x32_f16(a_h[m], b_h, acc[m][n], 0, 0, 0);
                acc[m][n] = __builtin_amdgcn_mfma_f32_16x16x32_f16(a_h[m], b_l, acc[m][n], 0, 0, 0);
                acc[m][n] = __builtin_amdgcn_mfma_f32_16x16x32_f16(a_l[m], b_h, acc[m][n], 0, 0, 0);
            }
        }
    }

    #pragma unroll
    for (int n = 0; n < 4; ++n) {
        int el = n * 16 + l15;
        size_t row = (size_t)(mb + el);
        #pragma unroll
        for (int m = 0; m < 2; ++m) {
            int fb = wv * 32 + m * 16 + quad * 4;
            f4_t o;
            #pragma unroll
            for (int r = 0; r < 4; ++r) o[r] = acc[m][n][r];
            *(f4_t*)&Cout[row * 128 + fb] = o;
        }
    }
}

// ---------------- fused node: h += (ssp(agg@Wl2+bl2)) @ Wl + bl ----------------
__launch_bounds__(256)
__global__ void gemm_node2(const float* __restrict__ agg,
                           const _Float16* __restrict__ w2th, const _Float16* __restrict__ w2tl,
                           const _Float16* __restrict__ wlth, const _Float16* __restrict__ wltl,
                           const float* __restrict__ bl2, const float* __restrict__ bl,
                           float* __restrict__ h) {
    __shared__ _Float16 aH[64 * 136];
    __shared__ _Float16 aL[64 * 136];
    int t = threadIdx.x;
    int mb = blockIdx.x * 64;
    #pragma unroll
    for (int j = 0; j < 8; ++j) {
        int idx = t + j * 256;
        int row = idx >> 5, c4 = idx & 31;
        f4_t v = *(const f4_t*)&agg[(size_t)(mb + row) * HID + c4 * 4];
        h4_t hh, ll;
        #pragma unroll
        for (int r = 0; r < 4; ++r) {
            _Float16 hx = (_Float16)v[r];
            hh[r] = hx; ll[r] = (_Float16)(v[r] - (float)hx);
        }
        *(h4_t*)&aH[row * 136 + c4 * 4] = hh;
        *(h4_t*)&aL[row * 136 + c4 * 4] = ll;
    }
    __syncthreads();

    int wv = t >> 6, lane = t & 63, l15 = lane & 15, quad = lane >> 4;
    int fq = wv * 32 + quad * 4;
    f4_t acc[2][4];

    // ---- GEMM A: Wl2T @ aggT ----
    #pragma unroll
    for (int m = 0; m < 2; ++m)
        #pragma unroll
        for (int n = 0; n < 4; ++n) acc[m][n] = (f4_t)0.0f;
    for (int kc = 0; kc < 4; ++kc) {
        int k0 = kc * 32 + quad * 8;
        h8_t a_h[2], a_l[2];
        #pragma unroll
        for (int m = 0; m < 2; ++m) {
            int fr = wv * 32 + m * 16 + l15;
            a_h[m] = *(const h8_t*)&w2th[fr * 128 + k0];
            a_l[m] = *(const h8_t*)&w2tl[fr * 128 + k0];
        }
        #pragma unroll
        for (int n = 0; n < 4; ++n) {
            int er = n * 16 + l15;
            h8_t b_h = *(const h8_t*)&aH[er * 136 + k0];
            h8_t b_l = *(const h8_t*)&aL[er * 136 + k0];
            #pragma unroll
            for (int m = 0; m < 2; ++m) {
                acc[m][n] = __builtin_amdgcn_mfma_f32_16x16x32_f16(a_h[m], b_h, acc[m][n], 0, 0, 0);
                acc[m][n] = __builtin_amdgcn_mfma_f32_16x16x32_f16(a_h[m], b_l, acc[m][n], 0, 0, 0);
                acc[m][n] = __builtin_amdgcn_mfma_f32_16x16x32_f16(a_l[m], b_h, acc[m][n], 0, 0, 0);
            }
        }
    }
    f4_t b2v[2];
    b2v[0] = *(const f4_t*)&bl2[fq]; b2v[1] = *(const f4_t*)&bl2[fq + 16];
    __syncthreads();   // all waves done reading aH/aL

    // epilogue A: ssp, split, write t1 back into aH/aL ([atom][feat])
    #pragma unroll
    for (int m = 0; m < 2; ++m)
        #pragma unroll
        for (int n = 0; n < 4; ++n) {
            int el = n * 16 + l15;
            int fb = wv * 32 + m * 16 + quad * 4;
            h4_t hh, ll;
            #pragma unroll
            for (int r = 0; r < 4; ++r) {
                float sv = ssp_f(acc[m][n][r] + b2v[m][r]);
                _Float16 hx = (_Float16)sv;
                hh[r] = hx;
                ll[r] = (_Float16)(sv - (float)hx);
            }
            *(h4_t*)&aH[el * 136 + fb] = hh;
            *(h4_t*)&aL[el * 136 + fb] = ll;
        }
    __syncthreads();

    // ---- GEMM B: WlT @ t1T ----
    #pragma unroll
    for (int m = 0; m < 2; ++m)
        #pragma unroll
        for (int n = 0; n < 4; ++n) acc[m][n] = (f4_t)0.0f;
    for (int kc = 0; kc < 4; ++kc) {
        int k0 = kc * 32 + quad * 8;
        h8_t a_h[2], a_l[2];
        #pragma unroll
        for (int m = 0; m < 2; ++m) {
            int fr = wv * 32 + m * 16 + l15;
            a_h[m] = *(const h8_t*)&wlth[fr * 128 + k0];
            a_l[m] = *(const h8_t*)&wltl[fr * 128 + k0];
        }
        #pragma unroll
        for (int n = 0; n < 4; ++n) {
            int er = n * 16 + l15;
            h8_t b_h = *(const h8_t*)&aH[er * 136 + k0];
            h8_t b_l = *(const h8_t*)&aL[er * 136 + k0];
            #pragma unroll
            for (int m = 0; m < 2; ++m) {
                acc[m][n] = __builtin_amdgcn_mfma_f32_16x16x32_f16(a_h[m], b_h, acc[m][n], 0, 0, 0);
                acc[m][n] = __builtin_amdgcn_mfma_f32_16x16x32_f16(a_h[m], b_l, acc[m][n], 0, 0, 0);
                acc[m][n] = __builtin_amdgcn_mfma_f32_16x16x32_f16(a_l[m], b_h, acc[m][n], 0, 0, 0);
            }
        }
    }
    f4_t blv[2];
    blv[0] = *(const f4_t*)&bl[fq]; blv[1] = *(const f4_t*)&bl[fq + 16];

    #pragma unroll
    for (int n = 0; n < 4; ++n) {
        int el = n * 16 + l15;
        size_t row = (size_t)(mb + el);
        #pragma unroll
        for (int m = 0; m < 2; ++m) {
            int fb = wv * 32 + m * 16 + quad * 4;
            f4_t hv = *(const f4_t*)&h[row * 128 + fb];
            f4_t o;
            #pragma unroll
            for (int r = 0; r < 4; ++r) o[r] = hv[r] + acc[m][n][r] + blv[m][r];
            *(f4_t*)&h[row * 128 + fb] = o;
        }
    }
}

// ---------------- fused edge filter: ea + weights from global, t1 in LDS ----------------
#define T1_LDW 136
#define MROW 132

__launch_bounds__(256)
__global__ void edge_filter(const float* __restrict__ x, float* __restrict__ agg,
                            const int* __restrict__ sSrc, const int* __restrict__ sDst,
                            const float* __restrict__ Cb,
                            const _Float16* __restrict__ eaH, const _Float16* __restrict__ eaL,
                            const _Float16* __restrict__ w1h, const _Float16* __restrict__ w1l,
                            const _Float16* __restrict__ w2h, const _Float16* __restrict__ w2l,
                            const float* __restrict__ bf1, const float* __restrict__ bf2) {
    __shared__ __align__(16) unsigned char smem[34816];   // t1H/t1L [64][136]; msg overlays
    __shared__ float cL[64];
    __shared__ int dstl[64];
    __shared__ int srcl[64];

    _Float16* t1H = (_Float16*)smem;
    _Float16* t1L = (_Float16*)(smem + 17408);
    float*    msg = (float*)smem;                  // [64][132] after GEMM2

    int t = threadIdx.x;
    int eb = blockIdx.x * 64;
    int wv = t >> 6, lane = t & 63;
    int l15 = lane & 15, quad = lane >> 4;

    // phase 0: per-edge metadata (read before first barrier-protected use)
    if (t < 64) {
        int e = eb + t;
        srcl[t] = sSrc[e];
        dstl[t] = sDst[e];
        cL[t] = Cb[e];
    }

    int fq = wv*32 + quad*4;
    f4_t b1v[2], b2v[2];
    b1v[0] = *(const f4_t*)&bf1[fq];  b1v[1] = *(const f4_t*)&bf1[fq + 16];
    b2v[0] = *(const f4_t*)&bf2[fq];  b2v[1] = *(const f4_t*)&bf2[fq + 16];

    // ---- GEMM1: t1^T = W1T @ ea^T, K=64; both operands from global ----
    f4_t acc1[2][4];
    #pragma unroll
    for (int m = 0; m < 2; ++m)
        #pragma unroll
        for (int n = 0; n < 4; ++n) acc1[m][n] = (f4_t)0.0f;

    #pragma unroll
    for (int kc = 0; kc < 2; ++kc) {
        int k0 = kc*32 + quad*8;
        h8_t a_h[2], a_l[2], b_h[4], b_l[4];
        #pragma unroll
        for (int m = 0; m < 2; ++m) {
            int fr = wv*32 + m*16 + l15;
            a_h[m] = *(const h8_t*)&w1h[fr*64 + k0];
            a_l[m] = *(const h8_t*)&w1l[fr*64 + k0];
        }
        #pragma unroll
        for (int n = 0; n < 4; ++n) {
            size_t er = (size_t)(eb + n*16 + l15);
            b_h[n] = *(const h8_t*)&eaH[er*64 + k0];
            b_l[n] = *(const h8_t*)&eaL[er*64 + k0];
        }
        #pragma unroll
        for (int m = 0; m < 2; ++m)
            #pragma unroll
            for (int n = 0; n < 4; ++n) {
                acc1[m][n] = __builtin_amdgcn_mfma_f32_16x16x32_f16(a_h[m], b_h[n], acc1[m][n], 0, 0, 0);
                acc1[m][n] = __builtin_amdgcn_mfma_f32_16x16x32_f16(a_h[m], b_l[n], acc1[m][n], 0, 0, 0);
                acc1[m][n] = __builtin_amdgcn_mfma_f32_16x16x32_f16(a_l[m], b_h[n], acc1[m][n], 0, 0, 0);
            }
    }

    // epilogue1: bias + ssp, hi/lo split, t1[edge][filter] into LDS
    #pragma unroll
    for (int m = 0; m < 2; ++m)
        #pragma unroll
        for (int n = 0; n < 4; ++n) {
            int el = n*16 + l15;
            int fb = wv*32 + m*16 + quad*4;
            h4_t hh, ll;
            #pragma unroll
            for (int r = 0; r < 4; ++r) {
                float sv = ssp_f(acc1[m][n][r] + b1v[m][r]);
                _Float16 hx = (_Float16)sv;
                hh[r] = hx;
                ll[r] = (_Float16)(sv - (float)hx);
            }
            *(h4_t*)&t1H[el*T1_LDW + fb] = hh;
            *(h4_t*)&t1L[el*T1_LDW + fb] = ll;
        }
    __syncthreads();

    // ---- GEMM2: filt^T = W2T @ t1^T, K=128; W2 from global ----
    f4_t acc2[2][4];
    #pragma unroll
    for (int m = 0; m < 2; ++m)
        #pragma unroll
        for (int n = 0; n < 4; ++n) acc2[m][n] = (f4_t)0.0f;

    for (int kc = 0; kc < 4; ++kc) {
        int k0 = kc*32 + quad*8;
        h8_t a_h[2], a_l[2];
        #pragma unroll
        for (int m = 0; m < 2; ++m) {
            int fr = wv*32 + m*16 + l15;
            a_h[m] = *(const h8_t*)&w2h[fr*128 + k0];
            a_l[m] = *(const h8_t*)&w2l[fr*128 + k0];
        }
        #pragma unroll
        for (int n = 0; n < 4; ++n) {
            int er = n*16 + l15;
            h8_t b_h = *(const h8_t*)&t1H[er*T1_LDW + k0];
            h8_t b_l = *(const h8_t*)&t1L[er*T1_LDW + k0];
            #pragma unroll
            for (int m = 0; m < 2; ++m) {
                acc2[m][n] = __builtin_amdgcn_mfma_f32_16x16x32_f16(a_h[m], b_h, acc2[m][n], 0, 0, 0);
                acc2[m][n] = __builtin_amdgcn_mfma_f32_16x16x32_f16(a_h[m], b_l, acc2[m][n], 0, 0, 0);
                acc2[m][n] = __builtin_amdgcn_mfma_f32_16x16x32_f16(a_l[m], b_h, acc2[m][n], 0, 0, 0);
            }
        }
    }
    __syncthreads();   // t1 dead; msg overlays

    // epilogue2: *C, gather x[src], msg[edge][filter]
    #pragma unroll
    for (int n = 0; n < 4; ++n) {
        int el = n*16 + l15;
        float ce = cL[el];
        int s = srcl[el];
        #pragma unroll
        for (int m = 0; m < 2; ++m) {
            int fb = wv*32 + m*16 + quad*4;
            f4_t xr = *(const f4_t*)&x[(size_t)s * HID + fb];
            f4_t o;
            #pragma unroll
            for (int r = 0; r < 4; ++r)
                o[r] = (acc2[m][n][r] + b2v[m][r]) * ce * xr[r];
            *(f4_t*)&msg[el*MROW + fb] = o;
        }
    }
    __syncthreads();

    // segmented reduction over sorted dst
    int f = t & 127, hf = t >> 7;
    int ib = hf * 32;
    float run = 0.0f;
    int cur = dstl[ib];
    for (int i = ib; i < ib + 32; ++i) {
        int dnow = dstl[i];
        if (dnow != cur) {
            atomicAdd(&agg[(size_t)cur * HID + f], run);
            run = 0.0f;
            cur = dnow;
        }
        run += msg[i*MROW + f];
    }
    atomicAdd(&agg[(size_t)cur * HID + f], run);
}

// ---------------- readout ----------------
__launch_bounds__(256)
__global__ void readout1(const float* __restrict__ h, const float* __restrict__ Wo1,
                         const float* __restrict__ bo1, const float* __restrict__ Wo2,
                         const float* __restrict__ bo2, float* __restrict__ accum) {
    __shared__ float w1[128 * 64];
    __shared__ float part[4];
    int t = threadIdx.x;
    for (int i = t; i < 128 * 16; i += 256)
        ((float4*)w1)[i] = ((const float4*)Wo1)[i];
    __syncthreads();
    int f = t & 63, wv = t >> 6;
    float b = bo1[f], w2v = Wo2[f];
    float lsum = 0.0f;
    for (int a = 0; a < 16; ++a) {
        int n = blockIdx.x * 64 + wv * 16 + a;
        const float* hr = &h[(size_t)n * HID];
        float acc = b;
        #pragma unroll 16
        for (int k = 0; k < 128; ++k)
            acc = fmaf(hr[k], w1[k*64 + f], acc);
        lsum += ssp_f(acc) * w2v;
    }
    #pragma unroll
    for (int off = 32; off > 0; off >>= 1)
        lsum += __shfl_down(lsum, off, 64);
    if (f == 0) part[wv] = lsum;
    __syncthreads();
    if (t == 0)
        atomicAdd(accum, part[0] + part[1] + part[2] + part[3] + 64.0f * bo2[0]);
}

__global__ void readout2(const float* __restrict__ accum, float* __restrict__ out) {
    out[0] = fmaxf(accum[0], 0.0f);
}

extern "C" void kernel_launch(void* const* d_in, const int* in_sizes, int n_in,
                              void* d_out, int out_size, void* d_ws, size_t ws_size,
                              hipStream_t stream) {
    const int*   z   = (const int*)d_in[0];
    const float* pos = (const float*)d_in[1];
    const int*   ei  = (const int*)d_in[2];
    const float* emb = (const float*)d_in[3];
    const float* Wf1 = (const float*)d_in[4];
    const float* bf1 = (const float*)d_in[5];
    const float* Wf2 = (const float*)d_in[6];
    const float* bf2 = (const float*)d_in[7];
    const float* Wl1 = (const float*)d_in[8];
    const float* Wl2 = (const float*)d_in[9];
    const float* bl2 = (const float*)d_in[10];
    const float* Wl  = (const float*)d_in[11];
    const float* bl  = (const float*)d_in[12];
    const float* Wo1 = (const float*)d_in[13];
    const float* bo1 = (const float*)d_in[14];
    const float* Wo2 = (const float*)d_in[15];
    const float* bo2 = (const float*)d_in[16];
    float* out = (float*)d_out;

    _Float16* w1h = (_Float16*)d_ws;                       // NI*8192
    _Float16* w1l = w1h + NI * 8192;
    _Float16* w2h = w1l + NI * 8192;                       // NI*16384
    _Float16* w2l = w2h + NI * 16384;
    _Float16* wnh = w2l + NI * 16384;                      // 3*NI*16384
    _Float16* wnl = wnh + 3 * NI * 16384;
    _Float16* eaH = wnl + 3 * NI * 16384;                  // E*64
    _Float16* eaL = eaH + (size_t)NEDGE * 64;
    float* Cb  = (float*)(eaL + (size_t)NEDGE * 64);       // E
    float* h   = Cb + NEDGE;
    float* x   = h   + (size_t)NATOM * HID;
    float* agg = x   + (size_t)NATOM * HID;
    float* accum = agg + (size_t)NATOM * HID;              // 4
    int* cnt  = (int*)(accum + 4);                         // N
    int* offs = cnt + NATOM;                               // N+4
    int* sSrc = offs + NATOM + 4;                          // E
    int* sDst = sSrc + NEDGE;                              // E

    fill0<<<NATOM/4/256, 256, 0, stream>>>((float*)cnt, NATOM/4);
    hist_k<<<NEDGE/256, 256, 0, stream>>>(ei, cnt);
    scan_k<<<1, 256, 0, stream>>>(cnt, offs);
    fill0<<<NATOM/4/256, 256, 0, stream>>>((float*)cnt, NATOM/4);
    scatter_k<<<NEDGE/256, 256, 0, stream>>>(ei, offs, cnt, sSrc, sDst);

    edge_pre<<<NEDGE/256, 256, 0, stream>>>(pos, sSrc, sDst, eaH, eaL, Cb);
    wprep<<<(NI*8192 + NI*16384 + 3*NI*16384)/256, 256, 0, stream>>>(
        Wf1, Wf2, Wl1, Wl2, Wl, w1h, w1l, w2h, w2l, wnh, wnl);
    embed_k<<<(NATOM*HID)/256, 256, 0, stream>>>(z, emb, h);

    for (int i = 0; i < NI; ++i) {
        gemm_node_mfma<<<256, 256, 0, stream>>>(h, wnh + (size_t)(0*NI+i)*16384,
            wnl + (size_t)(0*NI+i)*16384, x);
        fill0<<<(NATOM*HID/4)/256, 256, 0, stream>>>(agg, NATOM*HID/4);
        edge_filter<<<NEDGE/64, 256, 0, stream>>>(x, agg, sSrc, sDst, Cb, eaH, eaL,
            w1h + (size_t)i*8192, w1l + (size_t)i*8192,
            w2h + (size_t)i*16384, w2l + (size_t)i*16384,
            bf1 + i*HID, bf2 + i*HID);
        gemm_node2<<<256, 256, 0, stream>>>(agg,
            wnh + (size_t)(1*NI+i)*16384, wnl + (size_t)(1*NI+i)*16384,
            wnh + (size_t)(2*NI+i)*16384, wnl + (size_t)(2*NI+i)*16384,
            bl2 + i*HID, bl + i*HID, h);
    }
    fill0<<<1, 256, 0, stream>>>(accum, 1);
    readout1<<<NATOM/64, 256, 0, stream>>>(h, Wo1, bo1, Wo2, bo2, accum);
    readout2<<<1, 1, 0, stream>>>(accum, out);
}

// Round 6
// 791.313 us; speedup vs baseline: 8.2283x; 1.1585x over previous
//
#include <hip/hip_runtime.h>
#include <math.h>

#define NATOM 16384
#define NEDGE 262144
#define HID 128
#define NG 50
#define NI 6

typedef _Float16 h8_t __attribute__((ext_vector_type(8)));
typedef _Float16 h4_t __attribute__((ext_vector_type(4)));
typedef float    f4_t __attribute__((ext_vector_type(4)));

__device__ __forceinline__ float ssp_f(float v) {
    float e = __expf(-fabsf(v));
    return fmaxf(v, 0.0f) + __logf(1.0f + e) - 0.69314718055994531f;
}

// ---------------- counting sort by dst ----------------
__global__ void fill0(float* __restrict__ p, int n4) {
    int i = blockIdx.x * 256 + threadIdx.x;
    if (i < n4) ((float4*)p)[i] = make_float4(0.f, 0.f, 0.f, 0.f);
}

__global__ void hist_k(const int* __restrict__ ei, int* __restrict__ cnt) {
    int e = blockIdx.x * 256 + threadIdx.x;
    if (e < NEDGE) atomicAdd(&cnt[ei[NEDGE + e]], 1);
}

__global__ void scan_k(const int* __restrict__ cnt, int* __restrict__ offs) {
    __shared__ int part[256];
    int t = threadIdx.x;
    int base = t * 64;
    int s = 0;
    for (int i = 0; i < 64; ++i) s += cnt[base + i];
    part[t] = s;
    __syncthreads();
    for (int off = 1; off < 256; off <<= 1) {
        int v = (t >= off) ? part[t - off] : 0;
        __syncthreads();
        part[t] += v;
        __syncthreads();
    }
    int r = part[t] - s;
    for (int i = 0; i < 64; ++i) { offs[base + i] = r; r += cnt[base + i]; }
    if (t == 255) offs[NATOM] = r;
}

__global__ void scatter_k(const int* __restrict__ ei, const int* __restrict__ offs,
                          int* __restrict__ cnt, int* __restrict__ sSrc, int* __restrict__ sDst) {
    int e = blockIdx.x * 256 + threadIdx.x;
    if (e >= NEDGE) return;
    int d = ei[NEDGE + e];
    int r = atomicAdd(&cnt[d], 1);
    int j = offs[d] + r;
    sSrc[j] = ei[e];
    sDst[j] = d;
}

// ---------------- edge precompute: gaussians hi/lo edge-major [e][64] ----------------
__global__ void edge_pre(const float* __restrict__ pos,
                         const int* __restrict__ sSrc, const int* __restrict__ sDst,
                         _Float16* __restrict__ eaH, _Float16* __restrict__ eaL,
                         float* __restrict__ Cb) {
    int j = blockIdx.x * 256 + threadIdx.x;
    if (j >= NEDGE) return;
    int s = sSrc[j], dd = sDst[j];
    float dx = pos[3*s]   - pos[3*dd];
    float dy = pos[3*s+1] - pos[3*dd+1];
    float dz = pos[3*s+2] - pos[3*dd+2];
    float d = sqrtf(dx*dx + dy*dy + dz*dz);
    Cb[j] = 0.5f * (cosf(d * 0.31415926535897931f) + 1.0f);
    const float delta = 10.0f / 49.0f;
    const float coeff = -0.5f / (delta * delta);
    #pragma unroll
    for (int gq = 0; gq < 8; ++gq) {
        h8_t hv, lv;
        #pragma unroll
        for (int r = 0; r < 8; ++r) {
            int g = gq * 8 + r;
            float v = 0.0f;
            if (g < NG) { float u = d - (float)g * delta; v = __expf(coeff * u * u); }
            _Float16 hh = (_Float16)v;
            hv[r] = hh;
            lv[r] = (_Float16)(v - (float)hh);
        }
        *(h8_t*)&eaH[(size_t)j * 64 + gq * 8] = hv;
        *(h8_t*)&eaL[(size_t)j * 64 + gq * 8] = lv;
    }
}

// ---------------- weight prep: transpose + fp16 hi/lo split ----------------
__global__ void wprep(const float* __restrict__ Wf1, const float* __restrict__ Wf2,
                      const float* __restrict__ Wl1, const float* __restrict__ Wl2,
                      const float* __restrict__ Wl,
                      _Float16* __restrict__ w1h, _Float16* __restrict__ w1l,
                      _Float16* __restrict__ w2h, _Float16* __restrict__ w2l,
                      _Float16* __restrict__ wnh, _Float16* __restrict__ wnl) {
    int idx = blockIdx.x * 256 + threadIdx.x;
    const int S1 = NI * 128 * 64, S2 = NI * 128 * 128;
    if (idx < S1) {
        int i = idx >> 13, r = idx & 8191, fo = r >> 6, k = r & 63;
        float v = (k < NG) ? Wf1[(size_t)i * NG * 128 + k * 128 + fo] : 0.0f;
        _Float16 hh = (_Float16)v;
        w1h[idx] = hh; w1l[idx] = (_Float16)(v - (float)hh);
        return;
    }
    idx -= S1;
    if (idx < S2) {
        int i = idx >> 14, r = idx & 16383, fo = r >> 7, k = r & 127;
        float v = Wf2[(size_t)i * 128 * 128 + k * 128 + fo];
        _Float16 hh = (_Float16)v;
        w2h[idx] = hh; w2l[idx] = (_Float16)(v - (float)hh);
        return;
    }
    idx -= S2;
    if (idx < 3 * S2) {
        int mi = idx >> 14;
        int r = idx & 16383, fo = r >> 7, k = r & 127;
        int m = mi / NI, i = mi % NI;
        const float* W = (m == 0) ? Wl1 : (m == 1) ? Wl2 : Wl;
        float v = W[(size_t)i * 128 * 128 + k * 128 + fo];
        _Float16 hh = (_Float16)v;
        wnh[idx] = hh; wnl[idx] = (_Float16)(v - (float)hh);
    }
}

// ---------------- embedding gather ----------------
__global__ void embed_k(const int* __restrict__ z, const float* __restrict__ emb,
                        float* __restrict__ h) {
    int tid = blockIdx.x * 256 + threadIdx.x;
    int n = tid >> 7, f = tid & 127;
    h[tid] = emb[z[n] * HID + f];
}

// ---------------- node GEMM via MFMA fp16 hi/lo (initial lin1 only) ----------------
__launch_bounds__(256)
__global__ void gemm_node_mfma(const float* __restrict__ A,
                               const _Float16* __restrict__ wth, const _Float16* __restrict__ wtl,
                               float* __restrict__ Cout) {
    __shared__ _Float16 aH[64 * 136];
    __shared__ _Float16 aL[64 * 136];
    int t = threadIdx.x;
    int mb = blockIdx.x * 64;
    #pragma unroll
    for (int j = 0; j < 8; ++j) {
        int idx = t + j * 256;
        int row = idx >> 5, c4 = idx & 31;
        f4_t v = *(const f4_t*)&A[(size_t)(mb + row) * HID + c4 * 4];
        h4_t hh, ll;
        #pragma unroll
        for (int r = 0; r < 4; ++r) {
            _Float16 hx = (_Float16)v[r];
            hh[r] = hx; ll[r] = (_Float16)(v[r] - (float)hx);
        }
        *(h4_t*)&aH[row * 136 + c4 * 4] = hh;
        *(h4_t*)&aL[row * 136 + c4 * 4] = ll;
    }
    __syncthreads();

    int wv = t >> 6, lane = t & 63, l15 = lane & 15, quad = lane >> 4;
    f4_t acc[2][4];
    #pragma unroll
    for (int m = 0; m < 2; ++m)
        #pragma unroll
        for (int n = 0; n < 4; ++n) acc[m][n] = (f4_t)0.0f;

    for (int kc = 0; kc < 4; ++kc) {
        int k0 = kc * 32 + quad * 8;
        h8_t a_h[2], a_l[2];
        #pragma unroll
        for (int m = 0; m < 2; ++m) {
            int fr = wv * 32 + m * 16 + l15;
            a_h[m] = *(const h8_t*)&wth[fr * 128 + k0];
            a_l[m] = *(const h8_t*)&wtl[fr * 128 + k0];
        }
        #pragma unroll
        for (int n = 0; n < 4; ++n) {
            int er = n * 16 + l15;
            h8_t b_h = *(const h8_t*)&aH[er * 136 + k0];
            h8_t b_l = *(const h8_t*)&aL[er * 136 + k0];
            #pragma unroll
            for (int m = 0; m < 2; ++m) {
                acc[m][n] = __builtin_amdgcn_mfma_f32_16x16x32_f16(a_h[m], b_h, acc[m][n], 0, 0, 0);
                acc[m][n] = __builtin_amdgcn_mfma_f32_16x16x32_f16(a_h[m], b_l, acc[m][n], 0, 0, 0);
                acc[m][n] = __builtin_amdgcn_mfma_f32_16x16x32_f16(a_l[m], b_h, acc[m][n], 0, 0, 0);
            }
        }
    }

    #pragma unroll
    for (int n = 0; n < 4; ++n) {
        int el = n * 16 + l15;
        size_t row = (size_t)(mb + el);
        #pragma unroll
        for (int m = 0; m < 2; ++m) {
            int fb = wv * 32 + m * 16 + quad * 4;
            f4_t o;
            #pragma unroll
            for (int r = 0; r < 4; ++r) o[r] = acc[m][n][r];
            *(f4_t*)&Cout[row * 128 + fb] = o;
        }
    }
}

// ---------------- fused node: h += ssp(agg@Wl2+bl2)@Wl + bl ; x = h@Wl1next ----------------
__launch_bounds__(256)
__global__ void gemm_node3(const float* __restrict__ agg,
                           const _Float16* __restrict__ w2th, const _Float16* __restrict__ w2tl,
                           const _Float16* __restrict__ wlth, const _Float16* __restrict__ wltl,
                           const _Float16* __restrict__ w1nh, const _Float16* __restrict__ w1nl,
                           const float* __restrict__ bl2, const float* __restrict__ bl,
                           float* __restrict__ h, float* __restrict__ x) {
    __shared__ _Float16 aH[64 * 136];
    __shared__ _Float16 aL[64 * 136];
    int t = threadIdx.x;
    int mb = blockIdx.x * 64;
    #pragma unroll
    for (int j = 0; j < 8; ++j) {
        int idx = t + j * 256;
        int row = idx >> 5, c4 = idx & 31;
        f4_t v = *(const f4_t*)&agg[(size_t)(mb + row) * HID + c4 * 4];
        h4_t hh, ll;
        #pragma unroll
        for (int r = 0; r < 4; ++r) {
            _Float16 hx = (_Float16)v[r];
            hh[r] = hx; ll[r] = (_Float16)(v[r] - (float)hx);
        }
        *(h4_t*)&aH[row * 136 + c4 * 4] = hh;
        *(h4_t*)&aL[row * 136 + c4 * 4] = ll;
    }
    __syncthreads();

    int wv = t >> 6, lane = t & 63, l15 = lane & 15, quad = lane >> 4;
    int fq = wv * 32 + quad * 4;
    f4_t acc[2][4];

    // GEMM A: Wl2T @ aggT
    #pragma unroll
    for (int m = 0; m < 2; ++m)
        #pragma unroll
        for (int n = 0; n < 4; ++n) acc[m][n] = (f4_t)0.0f;
    for (int kc = 0; kc < 4; ++kc) {
        int k0 = kc * 32 + quad * 8;
        h8_t a_h[2], a_l[2];
        #pragma unroll
        for (int m = 0; m < 2; ++m) {
            int fr = wv * 32 + m * 16 + l15;
            a_h[m] = *(const h8_t*)&w2th[fr * 128 + k0];
            a_l[m] = *(const h8_t*)&w2tl[fr * 128 + k0];
        }
        #pragma unroll
        for (int n = 0; n < 4; ++n) {
            int er = n * 16 + l15;
            h8_t b_h = *(const h8_t*)&aH[er * 136 + k0];
            h8_t b_l = *(const h8_t*)&aL[er * 136 + k0];
            #pragma unroll
            for (int m = 0; m < 2; ++m) {
                acc[m][n] = __builtin_amdgcn_mfma_f32_16x16x32_f16(a_h[m], b_h, acc[m][n], 0, 0, 0);
                acc[m][n] = __builtin_amdgcn_mfma_f32_16x16x32_f16(a_h[m], b_l, acc[m][n], 0, 0, 0);
                acc[m][n] = __builtin_amdgcn_mfma_f32_16x16x32_f16(a_l[m], b_h, acc[m][n], 0, 0, 0);
            }
        }
    }
    f4_t b2v[2];
    b2v[0] = *(const f4_t*)&bl2[fq]; b2v[1] = *(const f4_t*)&bl2[fq + 16];
    __syncthreads();

    // epilogue A: ssp, split, t1 into aH/aL
    #pragma unroll
    for (int m = 0; m < 2; ++m)
        #pragma unroll
        for (int n = 0; n < 4; ++n) {
            int el = n * 16 + l15;
            int fb = wv * 32 + m * 16 + quad * 4;
            h4_t hh, ll;
            #pragma unroll
            for (int r = 0; r < 4; ++r) {
                float sv = ssp_f(acc[m][n][r] + b2v[m][r]);
                _Float16 hx = (_Float16)sv;
                hh[r] = hx;
                ll[r] = (_Float16)(sv - (float)hx);
            }
            *(h4_t*)&aH[el * 136 + fb] = hh;
            *(h4_t*)&aL[el * 136 + fb] = ll;
        }
    __syncthreads();

    // GEMM B: WlT @ t1T
    #pragma unroll
    for (int m = 0; m < 2; ++m)
        #pragma unroll
        for (int n = 0; n < 4; ++n) acc[m][n] = (f4_t)0.0f;
    for (int kc = 0; kc < 4; ++kc) {
        int k0 = kc * 32 + quad * 8;
        h8_t a_h[2], a_l[2];
        #pragma unroll
        for (int m = 0; m < 2; ++m) {
            int fr = wv * 32 + m * 16 + l15;
            a_h[m] = *(const h8_t*)&wlth[fr * 128 + k0];
            a_l[m] = *(const h8_t*)&wltl[fr * 128 + k0];
        }
        #pragma unroll
        for (int n = 0; n < 4; ++n) {
            int er = n * 16 + l15;
            h8_t b_h = *(const h8_t*)&aH[er * 136 + k0];
            h8_t b_l = *(const h8_t*)&aL[er * 136 + k0];
            #pragma unroll
            for (int m = 0; m < 2; ++m) {
                acc[m][n] = __builtin_amdgcn_mfma_f32_16x16x32_f16(a_h[m], b_h, acc[m][n], 0, 0, 0);
                acc[m][n] = __builtin_amdgcn_mfma_f32_16x16x32_f16(a_h[m], b_l, acc[m][n], 0, 0, 0);
                acc[m][n] = __builtin_amdgcn_mfma_f32_16x16x32_f16(a_l[m], b_h, acc[m][n], 0, 0, 0);
            }
        }
    }
    f4_t blv[2];
    blv[0] = *(const f4_t*)&bl[fq]; blv[1] = *(const f4_t*)&bl[fq + 16];
    __syncthreads();   // all waves done reading t1 before overwrite

    // epilogue B: hnew = h + acc + bl; store h; split hnew into aH/aL
    #pragma unroll
    for (int n = 0; n < 4; ++n) {
        int el = n * 16 + l15;
        size_t row = (size_t)(mb + el);
        #pragma unroll
        for (int m = 0; m < 2; ++m) {
            int fb = wv * 32 + m * 16 + quad * 4;
            f4_t hv = *(const f4_t*)&h[row * 128 + fb];
            f4_t o;
            h4_t hh, ll;
            #pragma unroll
            for (int r = 0; r < 4; ++r) {
                o[r] = hv[r] + acc[m][n][r] + blv[m][r];
                _Float16 hx = (_Float16)o[r];
                hh[r] = hx; ll[r] = (_Float16)(o[r] - (float)hx);
            }
            *(f4_t*)&h[row * 128 + fb] = o;
            *(h4_t*)&aH[el * 136 + fb] = hh;
            *(h4_t*)&aL[el * 136 + fb] = ll;
        }
    }
    if (!w1nh) return;
    __syncthreads();

    // GEMM C: Wl1nextT @ hnewT -> x
    #pragma unroll
    for (int m = 0; m < 2; ++m)
        #pragma unroll
        for (int n = 0; n < 4; ++n) acc[m][n] = (f4_t)0.0f;
    for (int kc = 0; kc < 4; ++kc) {
        int k0 = kc * 32 + quad * 8;
        h8_t a_h[2], a_l[2];
        #pragma unroll
        for (int m = 0; m < 2; ++m) {
            int fr = wv * 32 + m * 16 + l15;
            a_h[m] = *(const h8_t*)&w1nh[fr * 128 + k0];
            a_l[m] = *(const h8_t*)&w1nl[fr * 128 + k0];
        }
        #pragma unroll
        for (int n = 0; n < 4; ++n) {
            int er = n * 16 + l15;
            h8_t b_h = *(const h8_t*)&aH[er * 136 + k0];
            h8_t b_l = *(const h8_t*)&aL[er * 136 + k0];
            #pragma unroll
            for (int m = 0; m < 2; ++m) {
                acc[m][n] = __builtin_amdgcn_mfma_f32_16x16x32_f16(a_h[m], b_h, acc[m][n], 0, 0, 0);
                acc[m][n] = __builtin_amdgcn_mfma_f32_16x16x32_f16(a_h[m], b_l, acc[m][n], 0, 0, 0);
                acc[m][n] = __builtin_amdgcn_mfma_f32_16x16x32_f16(a_l[m], b_h, acc[m][n], 0, 0, 0);
            }
        }
    }
    #pragma unroll
    for (int n = 0; n < 4; ++n) {
        int el = n * 16 + l15;
        size_t row = (size_t)(mb + el);
        #pragma unroll
        for (int m = 0; m < 2; ++m) {
            int fb = wv * 32 + m * 16 + quad * 4;
            f4_t o;
            #pragma unroll
            for (int r = 0; r < 4; ++r) o[r] = acc[m][n][r];
            *(f4_t*)&x[row * 128 + fb] = o;
        }
    }
}

// ---------------- edge filter: persistent weights, 4 tiles/block, prefetch ----------------
#define T1_LDW 136
#define MROW 132
#define EF_TPB 4

__launch_bounds__(256, 2)
__global__ void edge_filter(const float* __restrict__ x, float* __restrict__ agg,
                            const int* __restrict__ sSrc, const int* __restrict__ sDst,
                            const float* __restrict__ Cb,
                            const _Float16* __restrict__ eaH, const _Float16* __restrict__ eaL,
                            const _Float16* __restrict__ w1h, const _Float16* __restrict__ w1l,
                            const _Float16* __restrict__ w2h, const _Float16* __restrict__ w2l,
                            const float* __restrict__ bf1, const float* __restrict__ bf2) {
    __shared__ __align__(16) _Float16 eaHs[64 * 72];
    __shared__ __align__(16) _Float16 eaLs[64 * 72];
    __shared__ __align__(16) unsigned char t1mem[34816];   // t1H/t1L; msg overlays
    __shared__ float cL[64];
    __shared__ int dstl[64];
    __shared__ int srcl[64];

    _Float16* t1H = (_Float16*)t1mem;
    _Float16* t1L = (_Float16*)(t1mem + 17408);
    float*    msg = (float*)t1mem;

    int t = threadIdx.x;
    int wv = t >> 6, lane = t & 63;
    int l15 = lane & 15, quad = lane >> 4;
    int tile0 = blockIdx.x * EF_TPB;

    // persistent weight fragments
    h8_t w1fh[2][2], w1fl[2][2], w2fh[4][2], w2fl[4][2];
    #pragma unroll
    for (int kc = 0; kc < 2; ++kc) {
        int k0 = kc * 32 + quad * 8;
        #pragma unroll
        for (int m = 0; m < 2; ++m) {
            int fr = wv * 32 + m * 16 + l15;
            w1fh[kc][m] = *(const h8_t*)&w1h[fr * 64 + k0];
            w1fl[kc][m] = *(const h8_t*)&w1l[fr * 64 + k0];
        }
    }
    #pragma unroll
    for (int kc = 0; kc < 4; ++kc) {
        int k0 = kc * 32 + quad * 8;
        #pragma unroll
        for (int m = 0; m < 2; ++m) {
            int fr = wv * 32 + m * 16 + l15;
            w2fh[kc][m] = *(const h8_t*)&w2h[fr * 128 + k0];
            w2fl[kc][m] = *(const h8_t*)&w2l[fr * 128 + k0];
        }
    }
    int fq = wv * 32 + quad * 4;
    f4_t b1v[2], b2v[2];
    b1v[0] = *(const f4_t*)&bf1[fq];  b1v[1] = *(const f4_t*)&bf1[fq + 16];
    b2v[0] = *(const f4_t*)&bf2[fq];  b2v[1] = *(const f4_t*)&bf2[fq + 16];

    // prologue: meta + ea for tile0
    {
        int eb = tile0 * 64;
        if (t < 64) {
            srcl[t] = sSrc[eb + t];
            dstl[t] = sDst[eb + t];
            cL[t]   = Cb[eb + t];
        }
        #pragma unroll
        for (int c = 0; c < 4; ++c) {
            int ch = t + c * 256;
            int pl = ch >> 9, rem = ch & 511, e = rem >> 3, ks = rem & 7;
            h8_t v = *(const h8_t*)((pl ? eaL : eaH) + (size_t)(eb + e) * 64 + ks * 8);
            *(h8_t*)((pl ? eaLs : eaHs) + e * 72 + ks * 8) = v;
        }
    }
    __syncthreads();

    for (int tt = 0; tt < EF_TPB; ++tt) {
        if (tt > 0) {
            __syncthreads();            // bar1: prev msg/meta reads done
            if (t < 64) {
                int e = (tile0 + tt) * 64 + t;
                srcl[t] = sSrc[e];
                dstl[t] = sDst[e];
                cL[t]   = Cb[e];
            }
        }
        bool pre = (tt < EF_TPB - 1);
        // issue ea loads for next tile (consumed mid-tile)
        h8_t sreg[4];
        if (pre) {
            int ebn = (tile0 + tt + 1) * 64;
            #pragma unroll
            for (int c = 0; c < 4; ++c) {
                int ch = t + c * 256;
                int pl = ch >> 9, rem = ch & 511, e = rem >> 3, ks = rem & 7;
                sreg[c] = *(const h8_t*)((pl ? eaL : eaH) + (size_t)(ebn + e) * 64 + ks * 8);
            }
        }

        // ---- GEMM1: persistent W1 x ea(LDS) ----
        f4_t acc1[2][4];
        #pragma unroll
        for (int m = 0; m < 2; ++m)
            #pragma unroll
            for (int n = 0; n < 4; ++n) acc1[m][n] = (f4_t)0.0f;
        #pragma unroll
        for (int kc = 0; kc < 2; ++kc) {
            int k0 = kc * 32 + quad * 8;
            h8_t b_h[4], b_l[4];
            #pragma unroll
            for (int n = 0; n < 4; ++n) {
                int er = n * 16 + l15;
                b_h[n] = *(const h8_t*)&eaHs[er * 72 + k0];
                b_l[n] = *(const h8_t*)&eaLs[er * 72 + k0];
            }
            #pragma unroll
            for (int m = 0; m < 2; ++m)
                #pragma unroll
                for (int n = 0; n < 4; ++n) {
                    acc1[m][n] = __builtin_amdgcn_mfma_f32_16x16x32_f16(w1fh[kc][m], b_h[n], acc1[m][n], 0, 0, 0);
                    acc1[m][n] = __builtin_amdgcn_mfma_f32_16x16x32_f16(w1fh[kc][m], b_l[n], acc1[m][n], 0, 0, 0);
                    acc1[m][n] = __builtin_amdgcn_mfma_f32_16x16x32_f16(w1fl[kc][m], b_h[n], acc1[m][n], 0, 0, 0);
                }
        }

        // epilogue1: ssp + split -> t1 (overlays msg, safe after bar1)
        #pragma unroll
        for (int m = 0; m < 2; ++m)
            #pragma unroll
            for (int n = 0; n < 4; ++n) {
                int el = n * 16 + l15;
                int fb = wv * 32 + m * 16 + quad * 4;
                h4_t hh, ll;
                #pragma unroll
                for (int r = 0; r < 4; ++r) {
                    float sv = ssp_f(acc1[m][n][r] + b1v[m][r]);
                    _Float16 hx = (_Float16)sv;
                    hh[r] = hx;
                    ll[r] = (_Float16)(sv - (float)hx);
                }
                *(h4_t*)&t1H[el * T1_LDW + fb] = hh;
                *(h4_t*)&t1L[el * T1_LDW + fb] = ll;
            }
        __syncthreads();                // bar2: t1 ready; all waves past GEMM1

        // write prefetched ea into LDS (region free now)
        if (pre) {
            #pragma unroll
            for (int c = 0; c < 4; ++c) {
                int ch = t + c * 256;
                int pl = ch >> 9, rem = ch & 511, e = rem >> 3, ks = rem & 7;
                *(h8_t*)((pl ? eaLs : eaHs) + e * 72 + ks * 8) = sreg[c];
            }
        }
        // prefetch x[src] gather (completes under GEMM2)
        f4_t xr[4][2];
        #pragma unroll
        for (int n = 0; n < 4; ++n) {
            int el = n * 16 + l15;
            int s = srcl[el];
            #pragma unroll
            for (int m = 0; m < 2; ++m) {
                int fb = wv * 32 + m * 16 + quad * 4;
                xr[n][m] = *(const f4_t*)&x[(size_t)s * HID + fb];
            }
        }

        // ---- GEMM2: persistent W2 x t1(LDS) ----
        f4_t acc2[2][4];
        #pragma unroll
        for (int m = 0; m < 2; ++m)
            #pragma unroll
            for (int n = 0; n < 4; ++n) acc2[m][n] = (f4_t)0.0f;
        #pragma unroll
        for (int kc = 0; kc < 4; ++kc) {
            int k0 = kc * 32 + quad * 8;
            #pragma unroll
            for (int n = 0; n < 4; ++n) {
                int er = n * 16 + l15;
                h8_t b_h = *(const h8_t*)&t1H[er * T1_LDW + k0];
                h8_t b_l = *(const h8_t*)&t1L[er * T1_LDW + k0];
                #pragma unroll
                for (int m = 0; m < 2; ++m) {
                    acc2[m][n] = __builtin_amdgcn_mfma_f32_16x16x32_f16(w2fh[kc][m], b_h, acc2[m][n], 0, 0, 0);
                    acc2[m][n] = __builtin_amdgcn_mfma_f32_16x16x32_f16(w2fh[kc][m], b_l, acc2[m][n], 0, 0, 0);
                    acc2[m][n] = __builtin_amdgcn_mfma_f32_16x16x32_f16(w2fl[kc][m], b_h, acc2[m][n], 0, 0, 0);
                }
            }
        }
        __syncthreads();                // bar3: t1 reads done; ea writes landed

        // epilogue2: *C, *x[src] -> msg
        #pragma unroll
        for (int n = 0; n < 4; ++n) {
            int el = n * 16 + l15;
            float ce = cL[el];
            #pragma unroll
            for (int m = 0; m < 2; ++m) {
                int fb = wv * 32 + m * 16 + quad * 4;
                f4_t o;
                #pragma unroll
                for (int r = 0; r < 4; ++r)
                    o[r] = (acc2[m][n][r] + b2v[m][r]) * ce * xr[n][m][r];
                *(f4_t*)&msg[el * MROW + fb] = o;
            }
        }
        __syncthreads();                // bar4: msg ready

        // segmented reduction over sorted dst
        int f = t & 127, hf = t >> 7;
        int ib = hf * 32;
        float run = 0.0f;
        int cur = dstl[ib];
        for (int i = ib; i < ib + 32; ++i) {
            int dnow = dstl[i];
            if (dnow != cur) {
                atomicAdd(&agg[(size_t)cur * HID + f], run);
                run = 0.0f;
                cur = dnow;
            }
            run += msg[i * MROW + f];
        }
        atomicAdd(&agg[(size_t)cur * HID + f], run);
    }
}

// ---------------- readout ----------------
__launch_bounds__(256)
__global__ void readout1(const float* __restrict__ h, const float* __restrict__ Wo1,
                         const float* __restrict__ bo1, const float* __restrict__ Wo2,
                         const float* __restrict__ bo2, float* __restrict__ accum) {
    __shared__ float w1[128 * 64];
    __shared__ float part[4];
    int t = threadIdx.x;
    for (int i = t; i < 128 * 16; i += 256)
        ((float4*)w1)[i] = ((const float4*)Wo1)[i];
    __syncthreads();
    int f = t & 63, wv = t >> 6;
    float b = bo1[f], w2v = Wo2[f];
    float lsum = 0.0f;
    for (int a = 0; a < 16; ++a) {
        int n = blockIdx.x * 64 + wv * 16 + a;
        const float* hr = &h[(size_t)n * HID];
        float acc = b;
        #pragma unroll 16
        for (int k = 0; k < 128; ++k)
            acc = fmaf(hr[k], w1[k*64 + f], acc);
        lsum += ssp_f(acc) * w2v;
    }
    #pragma unroll
    for (int off = 32; off > 0; off >>= 1)
        lsum += __shfl_down(lsum, off, 64);
    if (f == 0) part[wv] = lsum;
    __syncthreads();
    if (t == 0)
        atomicAdd(accum, part[0] + part[1] + part[2] + part[3] + 64.0f * bo2[0]);
}

__global__ void readout2(const float* __restrict__ accum, float* __restrict__ out) {
    out[0] = fmaxf(accum[0], 0.0f);
}

extern "C" void kernel_launch(void* const* d_in, const int* in_sizes, int n_in,
                              void* d_out, int out_size, void* d_ws, size_t ws_size,
                              hipStream_t stream) {
    const int*   z   = (const int*)d_in[0];
    const float* pos = (const float*)d_in[1];
    const int*   ei  = (const int*)d_in[2];
    const float* emb = (const float*)d_in[3];
    const float* Wf1 = (const float*)d_in[4];
    const float* bf1 = (const float*)d_in[5];
    const float* Wf2 = (const float*)d_in[6];
    const float* bf2 = (const float*)d_in[7];
    const float* Wl1 = (const float*)d_in[8];
    const float* Wl2 = (const float*)d_in[9];
    const float* bl2 = (const float*)d_in[10];
    const float* Wl  = (const float*)d_in[11];
    const float* bl  = (const float*)d_in[12];
    const float* Wo1 = (const float*)d_in[13];
    const float* bo1 = (const float*)d_in[14];
    const float* Wo2 = (const float*)d_in[15];
    const float* bo2 = (const float*)d_in[16];
    float* out = (float*)d_out;

    _Float16* w1h = (_Float16*)d_ws;
    _Float16* w1l = w1h + NI * 8192;
    _Float16* w2h = w1l + NI * 8192;
    _Float16* w2l = w2h + NI * 16384;
    _Float16* wnh = w2l + NI * 16384;
    _Float16* wnl = wnh + 3 * NI * 16384;
    _Float16* eaH = wnl + 3 * NI * 16384;
    _Float16* eaL = eaH + (size_t)NEDGE * 64;
    float* Cb  = (float*)(eaL + (size_t)NEDGE * 64);
    float* h   = Cb + NEDGE;
    float* x   = h   + (size_t)NATOM * HID;
    float* agg = x   + (size_t)NATOM * HID;
    float* accum = agg + (size_t)NATOM * HID;
    int* cnt  = (int*)(accum + 4);
    int* offs = cnt + NATOM;
    int* sSrc = offs + NATOM + 4;
    int* sDst = sSrc + NEDGE;

    fill0<<<NATOM/4/256, 256, 0, stream>>>((float*)cnt, NATOM/4);
    hist_k<<<NEDGE/256, 256, 0, stream>>>(ei, cnt);
    scan_k<<<1, 256, 0, stream>>>(cnt, offs);
    fill0<<<NATOM/4/256, 256, 0, stream>>>((float*)cnt, NATOM/4);
    scatter_k<<<NEDGE/256, 256, 0, stream>>>(ei, offs, cnt, sSrc, sDst);

    edge_pre<<<NEDGE/256, 256, 0, stream>>>(pos, sSrc, sDst, eaH, eaL, Cb);
    wprep<<<(NI*8192 + NI*16384 + 3*NI*16384)/256, 256, 0, stream>>>(
        Wf1, Wf2, Wl1, Wl2, Wl, w1h, w1l, w2h, w2l, wnh, wnl);
    embed_k<<<(NATOM*HID)/256, 256, 0, stream>>>(z, emb, h);

    // initial lin1 (iteration 0)
    gemm_node_mfma<<<256, 256, 0, stream>>>(h, wnh + (size_t)0*16384,
        wnl + (size_t)0*16384, x);
    for (int i = 0; i < NI; ++i) {
        fill0<<<(NATOM*HID/4)/256, 256, 0, stream>>>(agg, NATOM*HID/4);
        edge_filter<<<NEDGE/64/EF_TPB, 256, 0, stream>>>(x, agg, sSrc, sDst, Cb, eaH, eaL,
            w1h + (size_t)i*8192, w1l + (size_t)i*8192,
            w2h + (size_t)i*16384, w2l + (size_t)i*16384,
            bf1 + i*HID, bf2 + i*HID);
        const _Float16* w1nh = (i < NI-1) ? wnh + (size_t)(i+1)*16384 : nullptr;
        const _Float16* w1nl = (i < NI-1) ? wnl + (size_t)(i+1)*16384 : nullptr;
        gemm_node3<<<256, 256, 0, stream>>>(agg,
            wnh + (size_t)(1*NI+i)*16384, wnl + (size_t)(1*NI+i)*16384,
            wnh + (size_t)(2*NI+i)*16384, wnl + (size_t)(2*NI+i)*16384,
            w1nh, w1nl, bl2 + i*HID, bl + i*HID, h, x);
    }
    fill0<<<1, 256, 0, stream>>>(accum, 1);
    readout1<<<NATOM/64, 256, 0, stream>>>(h, Wo1, bo1, Wo2, bo2, accum);
    readout2<<<1, 1, 0, stream>>>(accum, out);
}